// Round 1
// baseline (1161.860 us; speedup 1.0000x reference)
//
#include <hip/hip_runtime.h>
#include <math.h>

#define CHI 256
#define CHO 256
#define NB 4
#define NH 64
#define NW 64
#define NK 9
#define TC 16   // channel chunk for cols staging (LDS: 9*16*64*4 = 36 KB)

// ws layout (floats):
//   dyA   [B][9][H][W]  147456
//   dxA   [B][9][H][W]  147456
//   maskA [B][9][H][W]  147456
//   wT    [CHI][9][CHO] 589824
// total 1032192 floats = 4.13 MB

__global__ __launch_bounds__(256) void transpose_w(const float* __restrict__ weight,
                                                   float* __restrict__ wT) {
    int idx = blockIdx.x * 256 + threadIdx.x;   // 0 .. 589823
    int o  = idx & 255;
    int ck = idx >> 8;          // c*9 + k
    int c  = ck / 9;
    int k  = ck - c * 9;
    wT[idx] = weight[(o * CHI + c) * 9 + k];
}

__global__ __launch_bounds__(64) void offset_conv(const float* __restrict__ x,
                                                  const float* __restrict__ w_off,
                                                  const float* __restrict__ b_off,
                                                  float* __restrict__ dyA,
                                                  float* __restrict__ dxA,
                                                  float* __restrict__ maskA) {
    int k = blockIdx.x;   // 0..8
    int h = blockIdx.y;   // 0..63
    int b = blockIdx.z;   // 0..3
    int w = threadIdx.x;  // 0..63

    float a0 = b_off[k];
    float a1 = b_off[k + 9];
    float a2 = b_off[k + 18];

    const float* xb = x + (size_t)b * CHI * NH * NW;
    const float* w0 = w_off + (size_t)k * CHI * 9;
    const float* w1 = w_off + (size_t)(k + 9) * CHI * 9;
    const float* w2 = w_off + (size_t)(k + 18) * CHI * 9;

    for (int c = 0; c < CHI; ++c) {
        const float* xc  = xb + c * (NH * NW);
        const float* wc0 = w0 + c * 9;
        const float* wc1 = w1 + c * 9;
        const float* wc2 = w2 + c * 9;
#pragma unroll
        for (int i = 0; i < 3; ++i) {
            int y = h + i - 1;
            if (y >= 0 && y < NH) {
#pragma unroll
                for (int j = 0; j < 3; ++j) {
                    int xw = w + j - 1;
                    float xv = (xw >= 0 && xw < NW) ? xc[y * NW + xw] : 0.f;
                    int t = i * 3 + j;
                    a0 = fmaf(wc0[t], xv, a0);
                    a1 = fmaf(wc1[t], xv, a1);
                    a2 = fmaf(wc2[t], xv, a2);
                }
            }
        }
    }
    int oi = ((b * NK + k) * NH + h) * NW + w;
    dyA[oi]   = a0;
    dxA[oi]   = a1;
    maskA[oi] = 1.f / (1.f + __expf(-a2));
}

__global__ __launch_bounds__(256) void dcn_main(const float* __restrict__ x,
                                                const float* __restrict__ dyA,
                                                const float* __restrict__ dxA,
                                                const float* __restrict__ maskA,
                                                const float* __restrict__ wT,
                                                const float* __restrict__ bias,
                                                const float* __restrict__ gamma,
                                                const float* __restrict__ beta,
                                                const float* __restrict__ rmean,
                                                const float* __restrict__ rvar,
                                                float* __restrict__ out) {
    __shared__ int   s_y0[576], s_y1[576], s_x0[576], s_x1[576];
    __shared__ float s_w00[576], s_w01[576], s_w10[576], s_w11[576];
    __shared__ float s_cols[NK][TC][NW];

    int h   = blockIdx.x;
    int b   = blockIdx.y;
    int tid = threadIdx.x;
    int w   = tid & 63;
    int q   = __builtin_amdgcn_readfirstlane(tid >> 6);   // wave id 0..3 (o-quadrant)

    // ---- phase 0: per-(w,k) bilinear metadata ----
    for (int p = tid; p < 576; p += 256) {
        int k  = p >> 6;
        int pw = p & 63;
        int ii = ((b * NK + k) * NH + h) * NW + pw;
        float dy = dyA[ii], dx = dxA[ii], mv = maskA[ii];
        float py = (float)h  + (float)(k / 3 - 1) + dy;
        float px = (float)pw + (float)(k % 3 - 1) + dx;
        float y0f = floorf(py), x0f = floorf(px);
        int y0 = (int)y0f, x0 = (int)x0f;
        float ly = py - y0f, lx = px - x0f;
        bool vy0 = (y0 >= 0) && (y0 < NH);
        bool vy1 = (y0 >= -1) && (y0 < NH - 1);
        bool vx0 = (x0 >= 0) && (x0 < NW);
        bool vx1 = (x0 >= -1) && (x0 < NW - 1);
        s_y0[p] = min(max(y0, 0), NH - 1);
        s_y1[p] = min(max(y0 + 1, 0), NH - 1);
        s_x0[p] = min(max(x0, 0), NW - 1);
        s_x1[p] = min(max(x0 + 1, 0), NW - 1);
        s_w00[p] = (1.f - ly) * (1.f - lx) * mv * ((vy0 && vx0) ? 1.f : 0.f);
        s_w01[p] = (1.f - ly) * lx         * mv * ((vy0 && vx1) ? 1.f : 0.f);
        s_w10[p] = ly         * (1.f - lx) * mv * ((vy1 && vx0) ? 1.f : 0.f);
        s_w11[p] = ly         * lx         * mv * ((vy1 && vx1) ? 1.f : 0.f);
    }
    __syncthreads();

    float acc[64];
#pragma unroll
    for (int i = 0; i < 64; ++i) acc[i] = 0.f;

    const float* xb = x + (size_t)b * CHI * NH * NW;

    for (int c0 = 0; c0 < CHI; c0 += TC) {
        // ---- phase 1: build cols[k][cl][w] for this channel chunk ----
        for (int t = 0; t < (NK * TC) / 4; ++t) {        // 36 iters, q-partitioned
            int pair = q * ((NK * TC) / 4) + t;          // 0..143
            int k  = pair >> 4;                          // /TC
            int cl = pair & (TC - 1);
            int mi = (k << 6) + w;
            const float* xc = xb + (c0 + cl) * (NH * NW);
            int y0 = s_y0[mi], y1 = s_y1[mi], x0 = s_x0[mi], x1 = s_x1[mi];
            float v = s_w00[mi] * xc[(y0 << 6) + x0]
                    + s_w01[mi] * xc[(y0 << 6) + x1]
                    + s_w10[mi] * xc[(y1 << 6) + x0]
                    + s_w11[mi] * xc[(y1 << 6) + x1];
            s_cols[k][cl][w] = v;
        }
        __syncthreads();

        // ---- phase 2: accumulate 64 o's per wave ----
        for (int cl = 0; cl < TC; ++cl) {
#pragma unroll
            for (int k = 0; k < NK; ++k) {
                float val = s_cols[k][cl][w];
                const float* wrow = wT + (size_t)(((c0 + cl) * 9 + k) * CHO) + (q << 6);
#pragma unroll
                for (int o = 0; o < 64; ++o)
                    acc[o] = fmaf(val, wrow[o], acc[o]);
            }
        }
        __syncthreads();
    }

    // ---- epilogue: bias + BN(eval) + ReLU ----
#pragma unroll
    for (int o = 0; o < 64; ++o) {
        int oc = (q << 6) + o;
        float inv = gamma[oc] * rsqrtf(rvar[oc] + 1e-5f);
        float v = (acc[o] + bias[oc]) * inv + (beta[oc] - rmean[oc] * inv);
        v = fmaxf(v, 0.f);
        out[(((size_t)b * CHO + oc) * NH + h) * NW + w] = v;
    }
}

extern "C" void kernel_launch(void* const* d_in, const int* in_sizes, int n_in,
                              void* d_out, int out_size, void* d_ws, size_t ws_size,
                              hipStream_t stream) {
    const float* x      = (const float*)d_in[0];
    const float* w_off  = (const float*)d_in[1];
    const float* b_off  = (const float*)d_in[2];
    const float* weight = (const float*)d_in[3];
    const float* bias   = (const float*)d_in[4];
    const float* gamma  = (const float*)d_in[5];
    const float* beta   = (const float*)d_in[6];
    const float* rmean  = (const float*)d_in[7];
    const float* rvar   = (const float*)d_in[8];
    float* out = (float*)d_out;

    float* ws    = (float*)d_ws;
    float* dyA   = ws;
    float* dxA   = dyA + 147456;
    float* maskA = dxA + 147456;
    float* wT    = maskA + 147456;

    hipLaunchKernelGGL(transpose_w, dim3(589824 / 256), dim3(256), 0, stream, weight, wT);
    hipLaunchKernelGGL(offset_conv, dim3(NK, NH, NB), dim3(64), 0, stream,
                       x, w_off, b_off, dyA, dxA, maskA);
    hipLaunchKernelGGL(dcn_main, dim3(NH, NB), dim3(256), 0, stream,
                       x, dyA, dxA, maskA, wT, bias, gamma, beta, rmean, rvar, out);
}

// Round 2
// 555.579 us; speedup vs baseline: 2.0913x; 2.0913x over previous
//
#include <hip/hip_runtime.h>
#include <math.h>

#define NH 64
#define NW 64
#define NB 4
#define NKT 9
#define CHI 256
#define CHO 256
#define KSTEPS 72   // 9 taps * 256 ch / 32

typedef __attribute__((ext_vector_type(8))) short bf16x8;   // 8 bf16 = 4 VGPR (MFMA A/B frag)
typedef __attribute__((ext_vector_type(4))) float f32x4;    // MFMA C/D frag
typedef __attribute__((ext_vector_type(4))) unsigned short us4;

static __device__ __forceinline__ unsigned short f2bf(float f) {
    unsigned int u = __float_as_uint(f);
    u += 0x7fffu + ((u >> 16) & 1u);     // RNE
    return (unsigned short)(u >> 16);
}

// ws layout (floats): dyA[4*9*64*64], dxA[same], maskA[same], then wB bf16 [72][256][32]
#define N_OFF (NB * NKT * NH * NW)   // 147456

// ---- kernel 1: weight -> bf16 MFMA-B layout wB[kstep][o][kin] ----
__global__ __launch_bounds__(256) void prep_wB(const float* __restrict__ weight,
                                               unsigned short* __restrict__ wB) {
    int idx = blockIdx.x * 256 + threadIdx.x;   // 0 .. 589823
    int kin = idx & 31;
    int o   = (idx >> 5) & 255;
    int ks  = idx >> 13;                        // 0..71
    int K   = ks * 32 + kin;                    // K = tap*256 + c
    int kt  = K >> 8;
    int c   = K & 255;
    wB[idx] = f2bf(weight[((size_t)o * CHI + c) * 9 + kt]);
}

// ---- kernel 2: offset/mask 3x3 conv (fp32, LDS-staged x) ----
__global__ __launch_bounds__(256) void offset_conv_v2(const float* __restrict__ x,
        const float* __restrict__ w_off, const float* __restrict__ b_off,
        float* __restrict__ dyA, float* __restrict__ dxA, float* __restrict__ maskA) {
    __shared__ float sX[32 * 3 * 64];   // [ci][row i][w]
    int h = blockIdx.x, b = blockIdx.y;
    int tid = threadIdx.x;
    int w = tid & 63, q = tid >> 6;     // wave q handles 7 (or 6) output channels
    int ocb = q * 7;
    int noc = (ocb + 7 <= 27) ? 7 : (27 - ocb);

    float acc[7];
#pragma unroll
    for (int u = 0; u < 7; ++u) acc[u] = (u < noc) ? b_off[ocb + u] : 0.f;

    const float* xb = x + (size_t)b * CHI * NH * NW;

    for (int c0 = 0; c0 < CHI; c0 += 32) {
        __syncthreads();
        for (int e = tid; e < 32 * 3 * 64; e += 256) {
            int ci = e / 192, r = e - ci * 192;
            int i = r >> 6, ww = r & 63;
            int y = h + i - 1;
            sX[e] = (y >= 0 && y < NH) ? xb[(size_t)(c0 + ci) * 4096 + y * 64 + ww] : 0.f;
        }
        __syncthreads();
        for (int ci = 0; ci < 32; ++ci) {
            float xv[9];
#pragma unroll
            for (int i = 0; i < 3; ++i)
#pragma unroll
                for (int j = 0; j < 3; ++j) {
                    int ww = w + j - 1;
                    xv[i * 3 + j] = (ww >= 0 && ww < 64) ? sX[ci * 192 + i * 64 + ww] : 0.f;
                }
            int c = c0 + ci;
#pragma unroll
            for (int u = 0; u < 7; ++u) {
                if (u < noc) {
                    const float* wp = w_off + ((size_t)(ocb + u) * CHI + c) * 9;
#pragma unroll
                    for (int t = 0; t < 9; ++t) acc[u] = fmaf(wp[t], xv[t], acc[u]);
                }
            }
        }
    }

    for (int u = 0; u < noc; ++u) {
        int oc = ocb + u;
        if (oc < 9) {
            dyA[((b * 9 + oc) * 64 + h) * 64 + w] = acc[u];
        } else if (oc < 18) {
            dxA[((b * 9 + (oc - 9)) * 64 + h) * 64 + w] = acc[u];
        } else {
            maskA[((b * 9 + (oc - 18)) * 64 + h) * 64 + w] = 1.f / (1.f + expf(-acc[u]));
        }
    }
}

// ---- kernel 3: deformable sampling + bf16 MFMA GEMM + BN + ReLU ----
__global__ __launch_bounds__(512) void dcn_main_v2(const float* __restrict__ x,
        const float* __restrict__ dyA, const float* __restrict__ dxA,
        const float* __restrict__ maskA, const unsigned short* __restrict__ wB,
        const float* __restrict__ bias, const float* __restrict__ gamma,
        const float* __restrict__ beta, const float* __restrict__ rmean,
        const float* __restrict__ rvar, float* __restrict__ out) {
    __shared__ int4   s_o[576];            // clipped corner element offsets per (tap,px)
    __shared__ float4 s_w[576];            // mask-premultiplied bilinear weights
    __shared__ unsigned short sA[64 * 40]; // A-tile 64px x 32k bf16, rows padded to 40

    int h = blockIdx.x, b = blockIdx.y;
    int tid = threadIdx.x;
    int lane = tid & 63;
    int q = tid >> 6;                      // wave 0..7 -> o-range [32q, 32q+32)
    int px = lane;
    int ln = lane & 15, lk = lane >> 4;

    // phase 0: bilinear metadata per (tap, px)
    for (int p = tid; p < 576; p += 512) {
        int k = p >> 6, pw = p & 63;
        int ii = ((b * 9 + k) * 64 + h) * 64 + pw;
        float dy = dyA[ii], dx = dxA[ii], mv = maskA[ii];
        float py  = (float)h  + (float)(k / 3 - 1) + dy;
        float pxf = (float)pw + (float)(k % 3 - 1) + dx;
        float y0f = floorf(py), x0f = floorf(pxf);
        int y0 = (int)y0f, x0 = (int)x0f;
        float ly = py - y0f, lx = pxf - x0f;
        bool vy0 = (y0 >= 0) && (y0 < 64);
        bool vy1 = (y0 >= -1) && (y0 < 63);
        bool vx0 = (x0 >= 0) && (x0 < 64);
        bool vx1 = (x0 >= -1) && (x0 < 63);
        int y0c = min(max(y0, 0), 63), y1c = min(max(y0 + 1, 0), 63);
        int x0c = min(max(x0, 0), 63), x1c = min(max(x0 + 1, 0), 63);
        s_o[p] = make_int4(y0c * 64 + x0c, y0c * 64 + x1c, y1c * 64 + x0c, y1c * 64 + x1c);
        s_w[p] = make_float4((1.f - ly) * (1.f - lx) * mv * ((vy0 && vx0) ? 1.f : 0.f),
                             (1.f - ly) * lx         * mv * ((vy0 && vx1) ? 1.f : 0.f),
                             ly         * (1.f - lx) * mv * ((vy1 && vx0) ? 1.f : 0.f),
                             ly         * lx         * mv * ((vy1 && vx1) ? 1.f : 0.f));
    }

    f32x4 zf = {0.f, 0.f, 0.f, 0.f};
    f32x4 acc[4][2];
#pragma unroll
    for (int mt = 0; mt < 4; ++mt) { acc[mt][0] = zf; acc[mt][1] = zf; }

    const float* xb = x + (size_t)b * CHI * 4096;
    const bf16x8* wBv = (const bf16x8*)wB;

    __syncthreads();   // metadata ready

    for (int kt = 0; kt < 9; ++kt) {
        int4   o4 = s_o[kt * 64 + px];
        float4 w4 = s_w[kt * 64 + px];
        for (int c8 = 0; c8 < 8; ++c8) {
            int ks = kt * 8 + c8;
            // B fragments straight from global (L2-resident, coalesced 16B/lane)
            size_t bb = ((size_t)ks * 256 + q * 32 + ln) * 4 + lk;
            bf16x8 bf0 = wBv[bb];
            bf16x8 bf1 = wBv[bb + 64];

            // build A-tile: this thread covers c = c8*32 + q*4 + {0..3} for pixel px
            int cbase = c8 * 32 + q * 4;
            us4 pk;
#pragma unroll
            for (int j = 0; j < 4; ++j) {
                const float* xc = xb + (size_t)(cbase + j) * 4096;
                float v = w4.x * xc[o4.x] + w4.y * xc[o4.y]
                        + w4.z * xc[o4.z] + w4.w * xc[o4.w];
                unsigned short bfv = f2bf(v);
                if (j == 0) pk.x = bfv; else if (j == 1) pk.y = bfv;
                else if (j == 2) pk.z = bfv; else pk.w = bfv;
            }
            *(us4*)&sA[px * 40 + q * 4] = pk;
            __syncthreads();

            // MFMA: 4 m-tiles x 2 n-tiles
#pragma unroll
            for (int mt = 0; mt < 4; ++mt) {
                bf16x8 af = *(const bf16x8*)&sA[(mt * 16 + ln) * 40 + lk * 8];
                acc[mt][0] = __builtin_amdgcn_mfma_f32_16x16x32_bf16(af, bf0, acc[mt][0], 0, 0, 0);
                acc[mt][1] = __builtin_amdgcn_mfma_f32_16x16x32_bf16(af, bf1, acc[mt][1], 0, 0, 0);
            }
            __syncthreads();
        }
    }

    // epilogue: bias + BN(eval) + ReLU, float4 stores (full 64B line coverage per inst)
    int oc0 = q * 32 + ln;
#pragma unroll
    for (int nt = 0; nt < 2; ++nt) {
        int oc = oc0 + nt * 16;
        float inv = gamma[oc] * rsqrtf(rvar[oc] + 1e-5f);
        float sh  = beta[oc] - rmean[oc] * inv + bias[oc] * inv;
#pragma unroll
        for (int mt = 0; mt < 4; ++mt) {
            f32x4 a = acc[mt][nt];
            float4 r = make_float4(fmaxf(a.x * inv + sh, 0.f),
                                   fmaxf(a.y * inv + sh, 0.f),
                                   fmaxf(a.z * inv + sh, 0.f),
                                   fmaxf(a.w * inv + sh, 0.f));
            size_t oi = (((size_t)b * 256 + oc) * 64 + h) * 64 + mt * 16 + lk * 4;
            *(float4*)(out + oi) = r;
        }
    }
}

extern "C" void kernel_launch(void* const* d_in, const int* in_sizes, int n_in,
                              void* d_out, int out_size, void* d_ws, size_t ws_size,
                              hipStream_t stream) {
    const float* x      = (const float*)d_in[0];
    const float* w_off  = (const float*)d_in[1];
    const float* b_off  = (const float*)d_in[2];
    const float* weight = (const float*)d_in[3];
    const float* bias   = (const float*)d_in[4];
    const float* gamma  = (const float*)d_in[5];
    const float* beta   = (const float*)d_in[6];
    const float* rmean  = (const float*)d_in[7];
    const float* rvar   = (const float*)d_in[8];
    float* out = (float*)d_out;

    float* ws    = (float*)d_ws;
    float* dyA   = ws;
    float* dxA   = dyA + N_OFF;
    float* maskA = dxA + N_OFF;
    unsigned short* wB = (unsigned short*)(maskA + N_OFF);   // 589824 bf16

    hipLaunchKernelGGL(prep_wB, dim3(589824 / 256), dim3(256), 0, stream, weight, wB);
    hipLaunchKernelGGL(offset_conv_v2, dim3(NH, NB), dim3(256), 0, stream,
                       x, w_off, b_off, dyA, dxA, maskA);
    hipLaunchKernelGGL(dcn_main_v2, dim3(NH, NB), dim3(512), 0, stream,
                       x, dyA, dxA, maskA, wB, bias, gamma, beta, rmean, rvar, out);
}

// Round 3
// 355.605 us; speedup vs baseline: 3.2673x; 1.5624x over previous
//
#include <hip/hip_runtime.h>
#include <math.h>

#define NH 64
#define NW 64
#define NB 4
#define NKT 9
#define CHI 256
#define CHO 256

typedef __attribute__((ext_vector_type(8))) short bf16x8;   // 8 bf16 = 4 VGPR (MFMA A/B frag)
typedef __attribute__((ext_vector_type(4))) float f32x4;    // MFMA C/D frag
typedef __attribute__((ext_vector_type(4))) unsigned short us4;

static __device__ __forceinline__ unsigned short f2bf(float f) {
    unsigned int u = __float_as_uint(f);
    u += 0x7fffu + ((u >> 16) & 1u);     // RNE
    return (unsigned short)(u >> 16);
}

#define N_OFF (NB * NKT * NH * NW)   // 147456 per array

// ---- kernel 0: seed dy/dx/mask accumulators with bias ----
__global__ __launch_bounds__(256) void init_off(const float* __restrict__ b_off,
                                                float* __restrict__ dyA,
                                                float* __restrict__ dxA,
                                                float* __restrict__ maskA) {
    int idx = blockIdx.x * 256 + threadIdx.x;     // 0 .. 3*147456-1
    int arr = idx / N_OFF;
    int rem = idx - arr * N_OFF;
    int k = (rem >> 12) % 9;                      // rem = ((b*9+k)*64+h)*64+w
    float v = b_off[arr * 9 + k];
    float* p = (arr == 0) ? dyA : (arr == 1) ? dxA : maskA;
    p[rem] = v;
}

// ---- kernel 1: weight -> bf16 MFMA-B layout wB[kstep][o][kin] ----
__global__ __launch_bounds__(256) void prep_wB(const float* __restrict__ weight,
                                               unsigned short* __restrict__ wB) {
    int idx = blockIdx.x * 256 + threadIdx.x;   // 0 .. 589823
    int kin = idx & 31;
    int o   = (idx >> 5) & 255;
    int ks  = idx >> 13;                        // 0..71
    int K   = ks * 32 + kin;                    // K = tap*256 + c
    int kt  = K >> 8;
    int c   = K & 255;
    wB[idx] = f2bf(weight[((size_t)o * CHI + c) * 9 + kt]);
}

// ---- kernel 2: offset/mask 3x3 conv, K-split x4, fp32 HW atomics ----
__global__ __launch_bounds__(256) void offset_conv_v3(const float* __restrict__ x,
        const float* __restrict__ w_off,
        float* __restrict__ dyA, float* __restrict__ dxA, float* __restrict__ maskA) {
    __shared__ float sXp[32 * 3 * 66];   // [ci][row i][col 0..65], cols 0/65 are zero pads
    int h  = blockIdx.x, b = blockIdx.y, kc = blockIdx.z;
    int c0 = kc * 64;
    int tid = threadIdx.x;
    int w = tid & 63, q = tid >> 6;
    int ocb = q * 7;
    int noc = (ocb + 7 <= 27) ? 7 : (27 - ocb);   // 7,7,7,6

    float acc[7];
#pragma unroll
    for (int u = 0; u < 7; ++u) acc[u] = 0.f;

    const float* xb = x + (size_t)b * CHI * NH * NW;

    for (int chunk = 0; chunk < 64; chunk += 32) {
        __syncthreads();
        for (int e = tid; e < 32 * 3 * 66; e += 256) {
            int ci = e / 198;
            int r  = e - ci * 198;
            int i  = r / 66;
            int col = r - i * 66;
            int ww = col - 1;
            int y  = h + i - 1;
            float v = 0.f;
            if (ww >= 0 && ww < 64 && y >= 0 && y < 64)
                v = xb[(size_t)(c0 + chunk + ci) * 4096 + y * 64 + ww];
            sXp[e] = v;
        }
        __syncthreads();
        for (int ci = 0; ci < 32; ++ci) {
            float xv[9];
#pragma unroll
            for (int i = 0; i < 3; ++i)
#pragma unroll
                for (int j = 0; j < 3; ++j)
                    xv[i * 3 + j] = sXp[ci * 198 + i * 66 + w + j];
            int c = c0 + chunk + ci;
#pragma unroll
            for (int u = 0; u < 7; ++u) {
                if (u < noc) {
                    const float* wp = w_off + ((size_t)(ocb + u) * CHI + c) * 9;
#pragma unroll
                    for (int t = 0; t < 9; ++t) acc[u] = fmaf(wp[t], xv[t], acc[u]);
                }
            }
        }
    }

    for (int u = 0; u < noc; ++u) {
        int oc = ocb + u;
        float* base = (oc < 9) ? dyA : (oc < 18) ? dxA : maskA;
        int k = (oc < 9) ? oc : (oc < 18) ? oc - 9 : oc - 18;
        unsafeAtomicAdd(&base[((b * 9 + k) * 64 + h) * 64 + w], acc[u]);
    }
}

// ---- kernel 3: deformable sampling + bf16 MFMA GEMM + BN + ReLU ----
__global__ __launch_bounds__(512) void dcn_main_v3(const float* __restrict__ x,
        const float* __restrict__ dyA, const float* __restrict__ dxA,
        const float* __restrict__ maskA, const unsigned short* __restrict__ wB,
        const float* __restrict__ bias, const float* __restrict__ gamma,
        const float* __restrict__ beta, const float* __restrict__ rmean,
        const float* __restrict__ rvar, float* __restrict__ out) {
    __shared__ int4   s_o[576];                // clipped corner offsets per (tap,px)
    __shared__ float4 s_w[576];                // mask-premultiplied bilinear weights
    __shared__ unsigned short sA[2][64 * 40];  // double-buffered A-tile 64px x 32k bf16

    int h = blockIdx.x, b = blockIdx.y;
    int tid = threadIdx.x;
    int lane = tid & 63;
    int q = tid >> 6;                      // wave 0..7 -> o-range [32q, 32q+32)
    int px = lane;
    int ln = lane & 15, lk = lane >> 4;

    // phase 0: bilinear metadata per (tap, px); sigmoid applied here (maskA holds pre-act)
    for (int p = tid; p < 576; p += 512) {
        int k = p >> 6, pw = p & 63;
        int ii = ((b * 9 + k) * 64 + h) * 64 + pw;
        float dy = dyA[ii], dx = dxA[ii];
        float mv = 1.f / (1.f + __expf(-maskA[ii]));
        float py  = (float)h  + (float)(k / 3 - 1) + dy;
        float pxf = (float)pw + (float)(k % 3 - 1) + dx;
        float y0f = floorf(py), x0f = floorf(pxf);
        int y0 = (int)y0f, x0 = (int)x0f;
        float ly = py - y0f, lx = pxf - x0f;
        bool vy0 = (y0 >= 0) && (y0 < 64);
        bool vy1 = (y0 >= -1) && (y0 < 63);
        bool vx0 = (x0 >= 0) && (x0 < 64);
        bool vx1 = (x0 >= -1) && (x0 < 63);
        int y0c = min(max(y0, 0), 63), y1c = min(max(y0 + 1, 0), 63);
        int x0c = min(max(x0, 0), 63), x1c = min(max(x0 + 1, 0), 63);
        s_o[p] = make_int4(y0c * 64 + x0c, y0c * 64 + x1c, y1c * 64 + x0c, y1c * 64 + x1c);
        s_w[p] = make_float4((1.f - ly) * (1.f - lx) * mv * ((vy0 && vx0) ? 1.f : 0.f),
                             (1.f - ly) * lx         * mv * ((vy0 && vx1) ? 1.f : 0.f),
                             ly         * (1.f - lx) * mv * ((vy1 && vx0) ? 1.f : 0.f),
                             ly         * lx         * mv * ((vy1 && vx1) ? 1.f : 0.f));
    }

    f32x4 zf = {0.f, 0.f, 0.f, 0.f};
    f32x4 acc[4][2];
#pragma unroll
    for (int mt = 0; mt < 4; ++mt) { acc[mt][0] = zf; acc[mt][1] = zf; }

    const float* xb = x + (size_t)b * CHI * 4096;
    const bf16x8* wBv = (const bf16x8*)wB;

    __syncthreads();   // metadata ready

    // build A-tile slice for kstep ks into buffer buf
#define BUILD(ks, buf) do {                                                   \
        int kt_ = (ks) >> 3, c8_ = (ks) & 7;                                  \
        int mi_ = kt_ * 64 + px;                                              \
        int4   o4_ = s_o[mi_];                                                \
        float4 w4_ = s_w[mi_];                                                \
        int cbase_ = c8_ * 32 + q * 4;                                        \
        us4 pk_;                                                              \
        _Pragma("unroll")                                                     \
        for (int j_ = 0; j_ < 4; ++j_) {                                      \
            const float* xc_ = xb + (size_t)(cbase_ + j_) * 4096;             \
            float v_ = w4_.x * xc_[o4_.x] + w4_.y * xc_[o4_.y]                \
                     + w4_.z * xc_[o4_.z] + w4_.w * xc_[o4_.w];               \
            unsigned short bv_ = f2bf(v_);                                    \
            if (j_ == 0) pk_.x = bv_; else if (j_ == 1) pk_.y = bv_;          \
            else if (j_ == 2) pk_.z = bv_; else pk_.w = bv_;                  \
        }                                                                     \
        *(us4*)&sA[buf][px * 40 + q * 4] = pk_;                               \
    } while (0)

    BUILD(0, 0);
    size_t bb0 = ((size_t)q * 32 + ln) * 4 + lk;
    bf16x8 bf0 = wBv[bb0];
    bf16x8 bf1 = wBv[bb0 + 64];
    __syncthreads();

    for (int ks = 0; ks < 72; ++ks) {
        int cur = ks & 1;
        // A-fragments for current step first (ds_read early)
        bf16x8 af[4];
#pragma unroll
        for (int mt = 0; mt < 4; ++mt)
            af[mt] = *(const bf16x8*)&sA[cur][(mt * 16 + ln) * 40 + lk * 8];

        bf16x8 nb0, nb1;
        if (ks + 1 < 72) {
            size_t bb = ((size_t)(ks + 1) * 256 + q * 32 + ln) * 4 + lk;
            nb0 = wBv[bb];
            nb1 = wBv[bb + 64];
            BUILD(ks + 1, cur ^ 1);
        }

#pragma unroll
        for (int mt = 0; mt < 4; ++mt) {
            acc[mt][0] = __builtin_amdgcn_mfma_f32_16x16x32_bf16(af[mt], bf0, acc[mt][0], 0, 0, 0);
            acc[mt][1] = __builtin_amdgcn_mfma_f32_16x16x32_bf16(af[mt], bf1, acc[mt][1], 0, 0, 0);
        }
        if (ks + 1 < 72) { bf0 = nb0; bf1 = nb1; }
        __syncthreads();
    }
#undef BUILD

    // epilogue: bias + BN(eval) + ReLU, float4 stores
    int oc0 = q * 32 + ln;
#pragma unroll
    for (int nt = 0; nt < 2; ++nt) {
        int oc = oc0 + nt * 16;
        float inv = gamma[oc] * rsqrtf(rvar[oc] + 1e-5f);
        float sh  = beta[oc] - rmean[oc] * inv + bias[oc] * inv;
#pragma unroll
        for (int mt = 0; mt < 4; ++mt) {
            f32x4 a = acc[mt][nt];
            float4 r = make_float4(fmaxf(a.x * inv + sh, 0.f),
                                   fmaxf(a.y * inv + sh, 0.f),
                                   fmaxf(a.z * inv + sh, 0.f),
                                   fmaxf(a.w * inv + sh, 0.f));
            size_t oi = (((size_t)b * 256 + oc) * 64 + h) * 64 + mt * 16 + lk * 4;
            *(float4*)(out + oi) = r;
        }
    }
}

extern "C" void kernel_launch(void* const* d_in, const int* in_sizes, int n_in,
                              void* d_out, int out_size, void* d_ws, size_t ws_size,
                              hipStream_t stream) {
    const float* x      = (const float*)d_in[0];
    const float* w_off  = (const float*)d_in[1];
    const float* b_off  = (const float*)d_in[2];
    const float* weight = (const float*)d_in[3];
    const float* bias   = (const float*)d_in[4];
    const float* gamma  = (const float*)d_in[5];
    const float* beta   = (const float*)d_in[6];
    const float* rmean  = (const float*)d_in[7];
    const float* rvar   = (const float*)d_in[8];
    float* out = (float*)d_out;

    float* ws    = (float*)d_ws;
    float* dyA   = ws;
    float* dxA   = dyA + N_OFF;
    float* maskA = dxA + N_OFF;                              // holds pre-sigmoid
    unsigned short* wB = (unsigned short*)(maskA + N_OFF);   // 589824 bf16

    hipLaunchKernelGGL(init_off, dim3(3 * N_OFF / 256), dim3(256), 0, stream,
                       b_off, dyA, dxA, maskA);
    hipLaunchKernelGGL(prep_wB, dim3(589824 / 256), dim3(256), 0, stream, weight, wB);
    hipLaunchKernelGGL(offset_conv_v3, dim3(NH, NB, 4), dim3(256), 0, stream,
                       x, w_off, dyA, dxA, maskA);
    hipLaunchKernelGGL(dcn_main_v3, dim3(NH, NB), dim3(512), 0, stream,
                       x, dyA, dxA, maskA, wB, bias, gamma, beta, rmean, rvar, out);
}

// Round 4
// 252.874 us; speedup vs baseline: 4.5946x; 1.4063x over previous
//
#include <hip/hip_runtime.h>
#include <math.h>

#define NH 64
#define NW 64
#define NB 4
#define CHI 256
#define CHO 256

typedef __attribute__((ext_vector_type(8))) short bf16x8;   // 8 bf16 = 4 VGPR (MFMA A/B frag)
typedef __attribute__((ext_vector_type(4))) float f32x4;    // MFMA C/D frag
typedef __attribute__((ext_vector_type(2))) float f32x2;
typedef __attribute__((ext_vector_type(4))) unsigned short us4;

static __device__ __forceinline__ unsigned short f2bf(float f) {
    unsigned int u = __float_as_uint(f);
    u += 0x7fffu + ((u >> 16) & 1u);     // RNE
    return (unsigned short)(u >> 16);
}
static __device__ __forceinline__ f32x2 ld2(const float* p) {
    f32x2 r; __builtin_memcpy(&r, p, 8); return r;   // align-4 safe
}

#define N_OFF (NB * 9 * NH * NW)   // 147456 per array

// ---- kernel 1: pack both weight tensors to bf16 MFMA-B layouts ----
// wB  [72][256 o][32 kin]  (main conv, K = tap*256 + c, tap-major)
// wOB [72][32 oc][32 kin]  (offset conv, oc>=27 zero-padded)
__global__ __launch_bounds__(256) void prep_both(const float* __restrict__ weight,
                                                 const float* __restrict__ w_off,
                                                 unsigned short* __restrict__ wB,
                                                 unsigned short* __restrict__ wOB) {
    int bid = blockIdx.x;
    int tid = threadIdx.x;
    if (bid < 2304) {
        int idx = bid * 256 + tid;              // 0..589823
        int kin = idx & 31, o = (idx >> 5) & 255, ks = idx >> 13;
        int K = ks * 32 + kin, kt = K >> 8, c = K & 255;
        wB[idx] = f2bf(weight[((size_t)o * CHI + c) * 9 + kt]);
    } else {
        int idx = (bid - 2304) * 256 + tid;     // 0..73727
        int kin = idx & 31, oc = (idx >> 5) & 31, ks = idx >> 10;
        int K = ks * 32 + kin, kt = K >> 8, c = K & 255;
        wOB[idx] = (oc < 27) ? f2bf(w_off[((size_t)oc * CHI + c) * 9 + kt])
                             : (unsigned short)0;
    }
}

// ---- kernel 2: offset/mask conv as bf16 MFMA GEMM (M=16 px, N=32, K split x2 across waves) ----
__global__ __launch_bounds__(256) void offset_gemm(const float* __restrict__ x,
        const unsigned short* __restrict__ wOB, const float* __restrict__ b_off,
        float* __restrict__ dyA, float* __restrict__ dxA, float* __restrict__ maskA) {
    __shared__ unsigned short sA[2][2][16 * 40];   // [khalf][buf][px*40+kin]
    __shared__ float sRed[2][16][17];

    int h = blockIdx.x, b = blockIdx.y;
    int pxbase = blockIdx.z * 16;
    int tid = threadIdx.x;
    int lane = tid & 63, q = tid >> 6;
    int ln = lane & 15, lk = lane >> 4;
    int nt = q & 1, kh = q >> 1;   // wave -> (n-tile, k-half)

    const float* xb = x + (size_t)b * CHI * 4096;
    const bf16x8* wOBv = (const bf16x8*)wOB;

#define OBUILD(t, buf) do {                                                  \
        int half_ = tid >> 7;                                                \
        int ks_ = half_ * 36 + (t);                                          \
        int u_ = tid & 127;                                                  \
        int pxl_ = u_ & 15, kg_ = u_ >> 4;                                   \
        int kt_ = ks_ >> 3, c8_ = ks_ & 7;                                   \
        int y_ = h + (kt_ / 3) - 1;                                          \
        int xw_ = pxbase + pxl_ + (kt_ % 3) - 1;                             \
        bool ok_ = (y_ >= 0) && (y_ < 64) && (xw_ >= 0) && (xw_ < 64);       \
        int off_ = (ok_ ? y_ : 0) * 64 + (ok_ ? xw_ : 0);                    \
        float m_ = ok_ ? 1.f : 0.f;                                          \
        us4 pk_;                                                             \
        _Pragma("unroll")                                                    \
        for (int j_ = 0; j_ < 4; ++j_) {                                     \
            int c_ = c8_ * 32 + kg_ * 4 + j_;                                \
            float v_ = m_ * xb[(size_t)c_ * 4096 + off_];                    \
            unsigned short bv_ = f2bf(v_);                                   \
            if (j_ == 0) pk_.x = bv_; else if (j_ == 1) pk_.y = bv_;         \
            else if (j_ == 2) pk_.z = bv_; else pk_.w = bv_;                 \
        }                                                                    \
        *(us4*)&sA[half_][buf][pxl_ * 40 + kg_ * 4] = pk_;                   \
    } while (0)

    f32x4 acc = {0.f, 0.f, 0.f, 0.f};

    OBUILD(0, 0);
    bf16x8 bf = wOBv[((size_t)(kh * 36) * 32 + nt * 16 + ln) * 4 + lk];
    __syncthreads();

    for (int t = 0; t < 36; ++t) {
        int cur = t & 1;
        bf16x8 af = *(const bf16x8*)&sA[kh][cur][ln * 40 + lk * 8];
        bf16x8 nbf;
        if (t + 1 < 36) {
            nbf = wOBv[((size_t)(kh * 36 + t + 1) * 32 + nt * 16 + ln) * 4 + lk];
            OBUILD(t + 1, cur ^ 1);
        }
        acc = __builtin_amdgcn_mfma_f32_16x16x32_bf16(af, bf, acc, 0, 0, 0);
        if (t + 1 < 36) bf = nbf;
        __syncthreads();
    }
#undef OBUILD

    // combine the two k-halves through LDS, then store with bias folded in
    if (kh == 1) {
#pragma unroll
        for (int r = 0; r < 4; ++r) sRed[nt][lk * 4 + r][ln] = acc[r];
    }
    __syncthreads();
    if (kh == 0) {
        int oc = nt * 16 + ln;
        if (oc < 27) {
            int arr = oc / 9, k9 = oc - arr * 9;
            float* dst = (arr == 0) ? dyA : (arr == 1) ? dxA : maskA;
            float bb = b_off[oc];
#pragma unroll
            for (int r = 0; r < 4; ++r) {
                int px = pxbase + lk * 4 + r;
                dst[((b * 9 + k9) * 64 + h) * 64 + px] =
                    acc[r] + sRed[nt][lk * 4 + r][ln] + bb;
            }
        }
    }
}

// ---- kernel 3: deformable sampling + bf16 MFMA GEMM + BN + ReLU (M-split x2) ----
__global__ __launch_bounds__(512) void dcn_main_v4(const float* __restrict__ x,
        const float* __restrict__ dyA, const float* __restrict__ dxA,
        const float* __restrict__ maskA, const unsigned short* __restrict__ wB,
        const float* __restrict__ bias, const float* __restrict__ gamma,
        const float* __restrict__ beta, const float* __restrict__ rmean,
        const float* __restrict__ rvar, float* __restrict__ out) {
    __shared__ int2   s_po[288];               // (top,bottom) paired-corner base offsets
    __shared__ float4 s_cw[288];               // remapped bilinear weights (cA0,cB0,cA1,cB1)
    __shared__ unsigned short sA[2][32 * 40];  // double-buffered A-tile 32px x 32k bf16

    int h = blockIdx.x, b = blockIdx.y;
    int pxbase = blockIdx.z * 32;
    int tid = threadIdx.x;
    int lane = tid & 63, q = tid >> 6;
    int ln = lane & 15, lk = lane >> 4;
    int mt = q & 1, nb = q >> 1;               // wave -> (m-tile, 64-oc group)

    // phase 0: bilinear metadata per (tap, px); sigmoid applied here
    for (int p = tid; p < 288; p += 512) {
        int k = p >> 5, pwl = p & 31, pw = pxbase + pwl;
        int ii = ((b * 9 + k) * 64 + h) * 64 + pw;
        float dy = dyA[ii], dx = dxA[ii];
        float mv = 1.f / (1.f + __expf(-maskA[ii]));
        float py  = (float)h  + (float)(k / 3 - 1) + dy;
        float pxf = (float)pw + (float)(k % 3 - 1) + dx;
        float y0f = floorf(py), x0f = floorf(pxf);
        int y0 = (int)y0f, x0 = (int)x0f;
        float ly = py - y0f, lx = pxf - x0f;
        bool vy0 = (y0 >= 0) && (y0 < 64);
        bool vy1 = (y0 >= -1) && (y0 < 63);
        bool vx0 = (x0 >= 0) && (x0 < 64);
        bool vx1 = (x0 >= -1) && (x0 < 63);
        float w00 = (1.f - ly) * (1.f - lx) * mv * ((vy0 && vx0) ? 1.f : 0.f);
        float w01 = (1.f - ly) * lx         * mv * ((vy0 && vx1) ? 1.f : 0.f);
        float w10 = ly         * (1.f - lx) * mv * ((vy1 && vx0) ? 1.f : 0.f);
        float w11 = ly         * lx         * mv * ((vy1 && vx1) ? 1.f : 0.f);
        int y0c = min(max(y0, 0), 63), y1c = min(max(y0 + 1, 0), 63);
        int bx = min(max(x0, 0), 62);          // paired window [bx, bx+1]
        s_po[p] = make_int2(y0c * 64 + bx, y1c * 64 + bx);
        float cA0, cB0, cA1, cB1;
        if (x0 == bx)          { cA0 = w00; cB0 = w01; cA1 = w10; cB1 = w11; }
        else if (x0 + 1 == bx) { cA0 = w01; cB0 = 0.f; cA1 = w11; cB1 = 0.f; }  // x0 == -1
        else if (x0 == bx + 1) { cA0 = 0.f; cB0 = w00; cA1 = 0.f; cB1 = w10; }  // x0 == 63
        else                   { cA0 = 0.f; cB0 = 0.f; cA1 = 0.f; cB1 = 0.f; }
        s_cw[p] = make_float4(cA0, cB0, cA1, cB1);
    }

    f32x4 zf = {0.f, 0.f, 0.f, 0.f};
    f32x4 acc[4] = {zf, zf, zf, zf};
    const float* xb = x + (size_t)b * CHI * 4096;
    const bf16x8* wBv = (const bf16x8*)wB;

    __syncthreads();

#define DBUILD(ks, buf) do {                                                  \
        int kt_ = (ks) >> 3, c8_ = (ks) & 7;                                  \
        int pxl_ = tid & 31, cg_ = tid >> 5;                                  \
        int mi_ = kt_ * 32 + pxl_;                                            \
        int2   oo_ = s_po[mi_];                                               \
        float4 cw_ = s_cw[mi_];                                               \
        unsigned int pk_ = 0;                                                 \
        _Pragma("unroll")                                                     \
        for (int j_ = 0; j_ < 2; ++j_) {                                      \
            const float* xc_ = xb + (size_t)(c8_ * 32 + cg_ * 2 + j_) * 4096; \
            f32x2 t_ = ld2(xc_ + oo_.x);                                      \
            f32x2 u_ = ld2(xc_ + oo_.y);                                      \
            float v_ = cw_.x * t_.x + cw_.y * t_.y + cw_.z * u_.x + cw_.w * u_.y; \
            pk_ |= (unsigned int)f2bf(v_) << (16 * j_);                       \
        }                                                                     \
        *(unsigned int*)&sA[buf][pxl_ * 40 + cg_ * 2] = pk_;                  \
    } while (0)

    DBUILD(0, 0);
    bf16x8 bf[4], nbf[4];
#pragma unroll
    for (int j = 0; j < 4; ++j)
        bf[j] = wBv[((size_t)nb * 64 + j * 16 + ln) * 4 + lk];
    __syncthreads();

    for (int ks = 0; ks < 72; ++ks) {
        int cur = ks & 1;
        bf16x8 af = *(const bf16x8*)&sA[cur][(mt * 16 + ln) * 40 + lk * 8];
        if (ks + 1 < 72) {
#pragma unroll
            for (int j = 0; j < 4; ++j)
                nbf[j] = wBv[((size_t)(ks + 1) * 256 + nb * 64 + j * 16 + ln) * 4 + lk];
            DBUILD(ks + 1, cur ^ 1);
        }
#pragma unroll
        for (int j = 0; j < 4; ++j)
            acc[j] = __builtin_amdgcn_mfma_f32_16x16x32_bf16(af, bf[j], acc[j], 0, 0, 0);
        if (ks + 1 < 72) {
#pragma unroll
            for (int j = 0; j < 4; ++j) bf[j] = nbf[j];
        }
        __syncthreads();
    }
#undef DBUILD

    // epilogue: bias + BN(eval) + ReLU, float4 stores
#pragma unroll
    for (int j = 0; j < 4; ++j) {
        int oc = nb * 64 + j * 16 + ln;
        float inv = gamma[oc] * rsqrtf(rvar[oc] + 1e-5f);
        float sh  = beta[oc] - rmean[oc] * inv + bias[oc] * inv;
        f32x4 a = acc[j];
        float4 r = make_float4(fmaxf(a.x * inv + sh, 0.f),
                               fmaxf(a.y * inv + sh, 0.f),
                               fmaxf(a.z * inv + sh, 0.f),
                               fmaxf(a.w * inv + sh, 0.f));
        size_t oi = (((size_t)b * 256 + oc) * 64 + h) * 64 + pxbase + mt * 16 + lk * 4;
        *(float4*)(out + oi) = r;
    }
}

extern "C" void kernel_launch(void* const* d_in, const int* in_sizes, int n_in,
                              void* d_out, int out_size, void* d_ws, size_t ws_size,
                              hipStream_t stream) {
    const float* x      = (const float*)d_in[0];
    const float* w_off  = (const float*)d_in[1];
    const float* b_off  = (const float*)d_in[2];
    const float* weight = (const float*)d_in[3];
    const float* bias   = (const float*)d_in[4];
    const float* gamma  = (const float*)d_in[5];
    const float* beta   = (const float*)d_in[6];
    const float* rmean  = (const float*)d_in[7];
    const float* rvar   = (const float*)d_in[8];
    float* out = (float*)d_out;

    float* ws    = (float*)d_ws;
    float* dyA   = ws;
    float* dxA   = dyA + N_OFF;
    float* maskA = dxA + N_OFF;                              // pre-sigmoid
    unsigned short* wB  = (unsigned short*)(maskA + N_OFF);  // 589824 bf16
    unsigned short* wOB = wB + 589824;                       // 73728 bf16

    hipLaunchKernelGGL(prep_both, dim3(2304 + 288), dim3(256), 0, stream,
                       weight, w_off, wB, wOB);
    hipLaunchKernelGGL(offset_gemm, dim3(NH, NB, 4), dim3(256), 0, stream,
                       x, wOB, b_off, dyA, dxA, maskA);
    hipLaunchKernelGGL(dcn_main_v4, dim3(NH, NB, 2), dim3(512), 0, stream,
                       x, dyA, dxA, maskA, wB, bias, gamma, beta, rmean, rvar, out);
}

// Round 5
// 235.486 us; speedup vs baseline: 4.9339x; 1.0738x over previous
//
#include <hip/hip_runtime.h>
#include <math.h>

#define NH 64
#define NW 64
#define NB 4
#define CHI 256
#define CHO 256

typedef __attribute__((ext_vector_type(8))) short bf16x8;   // 8 bf16 = 4 VGPR (MFMA A/B frag)
typedef __attribute__((ext_vector_type(4))) float f32x4;    // MFMA C/D frag
typedef __attribute__((ext_vector_type(2))) float f32x2;
typedef __attribute__((ext_vector_type(4))) unsigned short us4;

static __device__ __forceinline__ unsigned short f2bf(float f) {
    unsigned int u = __float_as_uint(f);
    u += 0x7fffu + ((u >> 16) & 1u);     // RNE
    return (unsigned short)(u >> 16);
}
static __device__ __forceinline__ f32x2 ld2(const float* p) {
    f32x2 r; __builtin_memcpy(&r, p, 8); return r;   // align-4 safe
}

#define N_OFF (NB * 9 * NH * NW)   // 147456 per array

// K-order: ks = cc*9 + kt  (channel-chunk OUTER, tap INNER -> L1 catches 9x row reuse)
// wB  [72][256 o][32 kin]  kin -> channel cc*32+kin, tap kt
// wOB [72][32 oc][32 kin]

__global__ __launch_bounds__(256) void prep_both(const float* __restrict__ weight,
                                                 const float* __restrict__ w_off,
                                                 unsigned short* __restrict__ wB,
                                                 unsigned short* __restrict__ wOB) {
    int bid = blockIdx.x;
    int tid = threadIdx.x;
    if (bid < 2304) {
        int idx = bid * 256 + tid;              // 0..589823
        int kin = idx & 31, o = (idx >> 5) & 255, ks = idx >> 13;
        int cc = ks / 9, kt = ks - cc * 9;
        int c = cc * 32 + kin;
        wB[idx] = f2bf(weight[((size_t)o * CHI + c) * 9 + kt]);
    } else {
        int idx = (bid - 2304) * 256 + tid;     // 0..73727
        int kin = idx & 31, oc = (idx >> 5) & 31, ks = idx >> 10;
        int cc = ks / 9, kt = ks - cc * 9;
        int c = cc * 32 + kin;
        wOB[idx] = (oc < 27) ? f2bf(w_off[((size_t)oc * CHI + c) * 9 + kt])
                             : (unsigned short)0;
    }
}

// ---- kernel 2: offset/mask conv as bf16 MFMA GEMM, XCD-swizzled ----
__global__ __launch_bounds__(256) void offset_gemm(const float* __restrict__ x,
        const unsigned short* __restrict__ wOB, const float* __restrict__ b_off,
        float* __restrict__ dyA, float* __restrict__ dxA, float* __restrict__ maskA) {
    __shared__ unsigned short sA[2][2][16 * 40];   // [khalf][buf][px*40+kin]
    __shared__ float sRed[2][16][17];

    // swizzle: xcd = id%8 owns one (b, h-half); 1024 blocks
    int id = blockIdx.x;
    int xcd = id & 7, sl = id >> 3;                // sl 0..127
    int b = xcd >> 1;
    int h = (xcd & 1) * 32 + (sl & 31);
    int pxbase = (sl >> 5) * 16;                   // z 0..3

    int tid = threadIdx.x;
    int lane = tid & 63, q = tid >> 6;
    int ln = lane & 15, lk = lane >> 4;
    int nt = q & 1, kh = q >> 1;   // wave -> (n-tile, k-half)

    const float* xb = x + (size_t)b * CHI * 4096;
    const bf16x8* wOBv = (const bf16x8*)wOB;

#define OBUILD(cc2p, ktp, buf) do {                                          \
        int half_ = tid >> 7;                                                \
        int u_ = tid & 127;                                                  \
        int pxl_ = u_ & 15, kg_ = u_ >> 4;                                   \
        int y_ = h + (ktp) / 3 - 1;                                          \
        int xw_ = pxbase + pxl_ + (ktp) % 3 - 1;                             \
        bool ok_ = (y_ >= 0) && (y_ < 64) && (xw_ >= 0) && (xw_ < 64);       \
        int off_ = (ok_ ? y_ : 0) * 64 + (ok_ ? xw_ : 0);                    \
        float m_ = ok_ ? 1.f : 0.f;                                          \
        us4 pk_;                                                             \
        _Pragma("unroll")                                                    \
        for (int j_ = 0; j_ < 4; ++j_) {                                     \
            int c_ = (half_ * 4 + (cc2p)) * 32 + kg_ * 4 + j_;               \
            float v_ = m_ * xb[(size_t)c_ * 4096 + off_];                    \
            unsigned short bv_ = f2bf(v_);                                   \
            if (j_ == 0) pk_.x = bv_; else if (j_ == 1) pk_.y = bv_;         \
            else if (j_ == 2) pk_.z = bv_; else pk_.w = bv_;                 \
        }                                                                    \
        *(us4*)&sA[half_][buf][pxl_ * 40 + kg_ * 4] = pk_;                   \
    } while (0)

    f32x4 acc = {0.f, 0.f, 0.f, 0.f};

    OBUILD(0, 0, 0);
    bf16x8 bf = wOBv[((size_t)(kh * 36) * 32 + nt * 16 + ln) * 4 + lk];
    __syncthreads();

    for (int cc2 = 0; cc2 < 4; ++cc2) {
        for (int kt = 0; kt < 9; ++kt) {
            int t = cc2 * 9 + kt;
            int cur = t & 1;
            bf16x8 af = *(const bf16x8*)&sA[kh][cur][ln * 40 + lk * 8];
            bool more = (t + 1 < 36);
            int ncc2 = (kt == 8) ? cc2 + 1 : cc2;
            int nkt  = (kt == 8) ? 0 : kt + 1;
            bf16x8 nbf;
            if (more) {
                nbf = wOBv[((size_t)(kh * 36 + t + 1) * 32 + nt * 16 + ln) * 4 + lk];
                OBUILD(ncc2, nkt, cur ^ 1);
            }
            acc = __builtin_amdgcn_mfma_f32_16x16x32_bf16(af, bf, acc, 0, 0, 0);
            if (more) bf = nbf;
            __syncthreads();
        }
    }
#undef OBUILD

    // combine the two k-halves through LDS, then store with bias folded in
    if (kh == 1) {
#pragma unroll
        for (int r = 0; r < 4; ++r) sRed[nt][lk * 4 + r][ln] = acc[r];
    }
    __syncthreads();
    if (kh == 0) {
        int oc = nt * 16 + ln;
        if (oc < 27) {
            int arr = oc / 9, k9 = oc - arr * 9;
            float* dst = (arr == 0) ? dyA : (arr == 1) ? dxA : maskA;
            float bb = b_off[oc];
#pragma unroll
            for (int r = 0; r < 4; ++r) {
                int px = pxbase + lk * 4 + r;
                dst[((b * 9 + k9) * 64 + h) * 64 + px] =
                    acc[r] + sRed[nt][lk * 4 + r][ln] + bb;
            }
        }
    }
}

// ---- kernel 3: deformable sampling + bf16 MFMA GEMM + BN + ReLU, XCD-swizzled ----
__global__ __launch_bounds__(512) void dcn_main_v5(const float* __restrict__ x,
        const float* __restrict__ dyA, const float* __restrict__ dxA,
        const float* __restrict__ maskA, const unsigned short* __restrict__ wB,
        const float* __restrict__ bias, const float* __restrict__ gamma,
        const float* __restrict__ beta, const float* __restrict__ rmean,
        const float* __restrict__ rvar, float* __restrict__ out) {
    __shared__ int2   s_po[288];               // (top,bottom) paired-corner base offsets
    __shared__ float4 s_cw[288];               // remapped bilinear weights (cA0,cB0,cA1,cB1)
    __shared__ unsigned short sA[2][32 * 40];  // double-buffered A-tile 32px x 32k bf16

    // swizzle: xcd = id%8 owns one (b, h-half); 512 blocks
    int id = blockIdx.x;
    int xcd = id & 7, sl = id >> 3;            // sl 0..63
    int b = xcd >> 1;
    int h = (xcd & 1) * 32 + (sl & 31);
    int pxbase = (sl >> 5) * 32;               // z 0..1

    int tid = threadIdx.x;
    int lane = tid & 63, q = tid >> 6;
    int ln = lane & 15, lk = lane >> 4;
    int mt = q & 1, nb = q >> 1;               // wave -> (m-tile, 64-oc group)

    // phase 0: bilinear metadata per (tap, px); sigmoid applied here
    for (int p = tid; p < 288; p += 512) {
        int k = p >> 5, pwl = p & 31, pw = pxbase + pwl;
        int ii = ((b * 9 + k) * 64 + h) * 64 + pw;
        float dy = dyA[ii], dx = dxA[ii];
        float mv = 1.f / (1.f + __expf(-maskA[ii]));
        float py  = (float)h  + (float)(k / 3 - 1) + dy;
        float pxf = (float)pw + (float)(k % 3 - 1) + dx;
        float y0f = floorf(py), x0f = floorf(pxf);
        int y0 = (int)y0f, x0 = (int)x0f;
        float ly = py - y0f, lx = pxf - x0f;
        bool vy0 = (y0 >= 0) && (y0 < 64);
        bool vy1 = (y0 >= -1) && (y0 < 63);
        bool vx0 = (x0 >= 0) && (x0 < 64);
        bool vx1 = (x0 >= -1) && (x0 < 63);
        float w00 = (1.f - ly) * (1.f - lx) * mv * ((vy0 && vx0) ? 1.f : 0.f);
        float w01 = (1.f - ly) * lx         * mv * ((vy0 && vx1) ? 1.f : 0.f);
        float w10 = ly         * (1.f - lx) * mv * ((vy1 && vx0) ? 1.f : 0.f);
        float w11 = ly         * lx         * mv * ((vy1 && vx1) ? 1.f : 0.f);
        int y0c = min(max(y0, 0), 63), y1c = min(max(y0 + 1, 0), 63);
        int bx = min(max(x0, 0), 62);          // paired window [bx, bx+1]
        s_po[p] = make_int2(y0c * 64 + bx, y1c * 64 + bx);
        float cA0, cB0, cA1, cB1;
        if (x0 == bx)          { cA0 = w00; cB0 = w01; cA1 = w10; cB1 = w11; }
        else if (x0 + 1 == bx) { cA0 = w01; cB0 = 0.f; cA1 = w11; cB1 = 0.f; }  // x0 == -1
        else if (x0 == bx + 1) { cA0 = 0.f; cB0 = w00; cA1 = 0.f; cB1 = w10; }  // x0 == 63
        else                   { cA0 = 0.f; cB0 = 0.f; cA1 = 0.f; cB1 = 0.f; }
        s_cw[p] = make_float4(cA0, cB0, cA1, cB1);
    }

    f32x4 zf = {0.f, 0.f, 0.f, 0.f};
    f32x4 acc[4] = {zf, zf, zf, zf};
    const float* xb = x + (size_t)b * CHI * 4096;
    const bf16x8* wBv = (const bf16x8*)wB;

    __syncthreads();

#define DBUILD(ccp, ktp, buf) do {                                            \
        int pxl_ = tid & 31, cg_ = tid >> 5;                                  \
        int mi_ = (ktp) * 32 + pxl_;                                          \
        int2   oo_ = s_po[mi_];                                               \
        float4 cw_ = s_cw[mi_];                                               \
        unsigned int pk_ = 0;                                                 \
        _Pragma("unroll")                                                     \
        for (int j_ = 0; j_ < 2; ++j_) {                                      \
            const float* xc_ = xb + (size_t)((ccp) * 32 + cg_ * 2 + j_) * 4096; \
            f32x2 t_ = ld2(xc_ + oo_.x);                                      \
            f32x2 u_ = ld2(xc_ + oo_.y);                                      \
            float v_ = cw_.x * t_.x + cw_.y * t_.y + cw_.z * u_.x + cw_.w * u_.y; \
            pk_ |= (unsigned int)f2bf(v_) << (16 * j_);                       \
        }                                                                     \
        *(unsigned int*)&sA[buf][pxl_ * 40 + cg_ * 2] = pk_;                  \
    } while (0)

    DBUILD(0, 0, 0);
    bf16x8 bf[4], nbf[4];
#pragma unroll
    for (int j = 0; j < 4; ++j)
        bf[j] = wBv[((size_t)nb * 64 + j * 16 + ln) * 4 + lk];
    __syncthreads();

    for (int cc = 0; cc < 8; ++cc) {
        for (int kt = 0; kt < 9; ++kt) {
            int ks = cc * 9 + kt;
            int cur = ks & 1;
            bf16x8 af = *(const bf16x8*)&sA[cur][(mt * 16 + ln) * 40 + lk * 8];
            bool more = (ks + 1 < 72);
            int ncc = (kt == 8) ? cc + 1 : cc;
            int nkt = (kt == 8) ? 0 : kt + 1;
            if (more) {
#pragma unroll
                for (int j = 0; j < 4; ++j)
                    nbf[j] = wBv[((size_t)(ks + 1) * 256 + nb * 64 + j * 16 + ln) * 4 + lk];
                DBUILD(ncc, nkt, cur ^ 1);
            }
#pragma unroll
            for (int j = 0; j < 4; ++j)
                acc[j] = __builtin_amdgcn_mfma_f32_16x16x32_bf16(af, bf[j], acc[j], 0, 0, 0);
            if (more) {
#pragma unroll
                for (int j = 0; j < 4; ++j) bf[j] = nbf[j];
            }
            __syncthreads();
        }
    }
#undef DBUILD

    // epilogue: bias + BN(eval) + ReLU, float4 stores
#pragma unroll
    for (int j = 0; j < 4; ++j) {
        int oc = nb * 64 + j * 16 + ln;
        float inv = gamma[oc] * rsqrtf(rvar[oc] + 1e-5f);
        float sh  = beta[oc] - rmean[oc] * inv + bias[oc] * inv;
        f32x4 a = acc[j];
        float4 r = make_float4(fmaxf(a.x * inv + sh, 0.f),
                               fmaxf(a.y * inv + sh, 0.f),
                               fmaxf(a.z * inv + sh, 0.f),
                               fmaxf(a.w * inv + sh, 0.f));
        size_t oi = (((size_t)b * 256 + oc) * 64 + h) * 64 + pxbase + mt * 16 + lk * 4;
        *(float4*)(out + oi) = r;
    }
}

extern "C" void kernel_launch(void* const* d_in, const int* in_sizes, int n_in,
                              void* d_out, int out_size, void* d_ws, size_t ws_size,
                              hipStream_t stream) {
    const float* x      = (const float*)d_in[0];
    const float* w_off  = (const float*)d_in[1];
    const float* b_off  = (const float*)d_in[2];
    const float* weight = (const float*)d_in[3];
    const float* bias   = (const float*)d_in[4];
    const float* gamma  = (const float*)d_in[5];
    const float* beta   = (const float*)d_in[6];
    const float* rmean  = (const float*)d_in[7];
    const float* rvar   = (const float*)d_in[8];
    float* out = (float*)d_out;

    float* ws    = (float*)d_ws;
    float* dyA   = ws;
    float* dxA   = dyA + N_OFF;
    float* maskA = dxA + N_OFF;                              // pre-sigmoid
    unsigned short* wB  = (unsigned short*)(maskA + N_OFF);  // 589824 bf16
    unsigned short* wOB = wB + 589824;                       // 73728 bf16

    hipLaunchKernelGGL(prep_both, dim3(2304 + 288), dim3(256), 0, stream,
                       weight, w_off, wB, wOB);
    hipLaunchKernelGGL(offset_gemm, dim3(1024), dim3(256), 0, stream,
                       x, wOB, b_off, dyA, dxA, maskA);
    hipLaunchKernelGGL(dcn_main_v5, dim3(512), dim3(512), 0, stream,
                       x, dyA, dxA, maskA, wB, bias, gamma, beta, rmean, rvar, out);
}

// Round 6
// 231.283 us; speedup vs baseline: 5.0235x; 1.0182x over previous
//
#include <hip/hip_runtime.h>
#include <math.h>

#define NH 64
#define NW 64
#define NB 4
#define CHI 256
#define CHO 256
#define NSTEP 80   // 16 chan-chunks(16) * 5 tap-pairs (taps padded 9->10)

typedef __attribute__((ext_vector_type(8))) short bf16x8;   // 8 bf16 = 4 VGPR (MFMA A/B frag)
typedef __attribute__((ext_vector_type(4))) float f32x4;    // MFMA C/D frag

static __device__ __forceinline__ unsigned short f2bf(float f) {
    unsigned int u = __float_as_uint(f);
    u += 0x7fffu + ((u >> 16) & 1u);     // RNE
    return (unsigned short)(u >> 16);
}
static __device__ __forceinline__ float bflo(unsigned int p) {
    return __uint_as_float(p << 16);
}
static __device__ __forceinline__ float bfhi(unsigned int p) {
    return __uint_as_float(p & 0xffff0000u);
}

#define N_OFF (NB * 9 * NH * NW)   // 147456 per array

// ws layout:
//   dyA/dxA/maskA  float [147456] each (maskA pre-sigmoid)
//   wB   bf16 [80][256 o][32 kin]   kin = tp*16+ci -> tap=(s%5)*2+tp, ch=(s/5)*16+ci
//   wOB  bf16 [72][32 oc][32 kin]   ks = cc*9+kt, kin = ch within cc
//   xpair uint [B*CHI*4096]         (bf16(x[p]), bf16(x[p+1])) packed
// total ~20.0 MB

__global__ __launch_bounds__(256) void prep_all(const float* __restrict__ weight,
                                                const float* __restrict__ w_off,
                                                const float* __restrict__ x,
                                                unsigned short* __restrict__ wB,
                                                unsigned short* __restrict__ wOB,
                                                unsigned int* __restrict__ xpair) {
    int bid = blockIdx.x, tid = threadIdx.x;
    if (bid < 2560) {
        int idx = bid * 256 + tid;             // < 655360
        int kin = idx & 31, o = (idx >> 5) & 255, s = idx >> 13;
        int tp = kin >> 4, ci = kin & 15;
        int cc = s / 5, tpr = s - cc * 5;
        int tap = tpr * 2 + tp;
        int ch = cc * 16 + ci;
        wB[idx] = (tap < 9) ? f2bf(weight[((size_t)o * CHI + ch) * 9 + tap])
                            : (unsigned short)0;
    } else if (bid < 2560 + 288) {
        int idx = (bid - 2560) * 256 + tid;    // < 73728
        int kin = idx & 31, oc = (idx >> 5) & 31, ks = idx >> 10;
        int cc = ks / 9, kt = ks - cc * 9;
        int c = cc * 32 + kin;
        wOB[idx] = (oc < 27) ? f2bf(w_off[((size_t)oc * CHI + c) * 9 + kt])
                             : (unsigned short)0;
    } else {
        int idx = (bid - 2848) * 256 + tid;    // < 4194304
        int w = idx & 63;
        float lo = x[idx];
        float hi = (w < 63) ? x[idx + 1] : 0.f;
        xpair[idx] = (unsigned int)f2bf(lo) | ((unsigned int)f2bf(hi) << 16);
    }
}

// ---- kernel 2: offset/mask conv via shifted LDS windows + MFMA (no gathers) ----
__global__ __launch_bounds__(512) void offset_gemm_v6(const float* __restrict__ x,
        const unsigned short* __restrict__ wOB, const float* __restrict__ b_off,
        float* __restrict__ dyA, float* __restrict__ dxA, float* __restrict__ maskA) {
    __shared__ unsigned short sX[3 * 66 * 40];   // [(rw*66+pxp)*40 + ci] bf16, pxp 0/65 = halo

    int id = blockIdx.x;             // 256 blocks = (b, h)
    int xcd = id & 7, sl = id >> 3;  // sl 0..31
    int b = xcd >> 1;
    int h = (xcd & 1) * 32 + sl;

    int tid = threadIdx.x;
    int lane = tid & 63, q = tid >> 6;
    int ln = lane & 15, lk = lane >> 4;
    int mt = q >> 1, nt = q & 1;     // wave -> (16-px m-tile 0..3, 16-oc n-tile 0..1)

    const float* xb = x + (size_t)b * CHI * 4096;
    const bf16x8* wOBv = (const bf16x8*)wOB;

    // zero halo columns once (never overwritten)
    if (tid < 192) {
        int rw = tid >> 6, rem = tid & 63, side = rem >> 5, ci = rem & 31;
        sX[(rw * 66 + (side ? 65 : 0)) * 40 + ci] = 0;
    }

    f32x4 acc = {0.f, 0.f, 0.f, 0.f};
    bf16x8 bf = wOBv[((size_t)(nt * 16 + ln)) * 4 + lk];   // ks=0 frag

    for (int cc = 0; cc < 8; ++cc) {
        __syncthreads();   // prior cc reads done
        // stage 3 rows x 32 ch x 64 px, fp32 -> bf16
        for (int rep = 0; rep < 6; ++rep) {
            int e = rep * 512 + tid;          // 0..3071
            int px = e & 63;
            int t  = e >> 6;                  // 0..47
            int ci2 = t / 3, rw = t - ci2 * 3;
            int y = h + rw - 1;
            float v0 = 0.f, v1 = 0.f;
            if (y >= 0 && y < 64) {
                const float* xc = xb + (size_t)(cc * 32 + ci2 * 2) * 4096 + y * 64 + px;
                v0 = xc[0];
                v1 = xc[4096];
            }
            unsigned int pk = (unsigned int)f2bf(v0) | ((unsigned int)f2bf(v1) << 16);
            *(unsigned int*)&sX[(rw * 66 + 1 + px) * 40 + ci2 * 2] = pk;
        }
        __syncthreads();
#pragma unroll
        for (int kt = 0; kt < 9; ++kt) {
            int s = cc * 9 + kt;
            int rw = kt / 3, dxk = kt - rw * 3 - 1;
            int pxp = 1 + mt * 16 + ln + dxk;
            bf16x8 af = *(const bf16x8*)&sX[(rw * 66 + pxp) * 40 + lk * 8];
            bf16x8 nbf;
            bool more = (s + 1 < 72);
            if (more) nbf = wOBv[((size_t)(s + 1) * 32 + nt * 16 + ln) * 4 + lk];
            acc = __builtin_amdgcn_mfma_f32_16x16x32_bf16(af, bf, acc, 0, 0, 0);
            if (more) bf = nbf;
        }
    }

    int oc = nt * 16 + ln;
    if (oc < 27) {
        int arr = oc / 9, k9 = oc - arr * 9;
        float* dst = (arr == 0) ? dyA : (arr == 1) ? dxA : maskA;
        float bb = b_off[oc];
#pragma unroll
        for (int r = 0; r < 4; ++r) {
            int px = mt * 16 + lk * 4 + r;
            dst[((b * 9 + k9) * 64 + h) * 64 + px] = acc[r] + bb;
        }
    }
}

// ---- kernel 3: deformable sampling (bf16 pair-gathers) + MFMA GEMM + BN + ReLU ----
__global__ __launch_bounds__(512, 4) void dcn_main_v6(
        const unsigned int* __restrict__ xpair,
        const float* __restrict__ dyA, const float* __restrict__ dxA,
        const float* __restrict__ maskA, const unsigned short* __restrict__ wB,
        const float* __restrict__ bias, const float* __restrict__ gamma,
        const float* __restrict__ beta, const float* __restrict__ rmean,
        const float* __restrict__ rvar, float* __restrict__ out) {
    __shared__ int2   s_po[320];               // 10 taps x 32 px (tap 9 zero-pad)
    __shared__ float4 s_cw[320];
    __shared__ unsigned short sA[2][32 * 40];  // double-buffered A-tile 32px x 32kin

    int id = blockIdx.x;
    int xcd = id & 7, sl = id >> 3;            // 512 blocks
    int b = xcd >> 1;
    int h = (xcd & 1) * 32 + (sl & 31);
    int pxbase = (sl >> 5) * 32;

    int tid = threadIdx.x;
    int lane = tid & 63, q = tid >> 6;
    int ln = lane & 15, lk = lane >> 4;
    int mt = q & 1, nb = q >> 1;               // wave -> (m-tile, 64-oc group)

    // phase 0: bilinear metadata; sigmoid applied here (maskA holds pre-act)
    for (int p = tid; p < 320; p += 512) {
        int k = p >> 5, pwl = p & 31, pw = pxbase + pwl;
        if (k < 9) {
            int ii = ((b * 9 + k) * 64 + h) * 64 + pw;
            float dy = dyA[ii], dx = dxA[ii];
            float mv = 1.f / (1.f + __expf(-maskA[ii]));
            float py  = (float)h  + (float)(k / 3 - 1) + dy;
            float pxf = (float)pw + (float)(k % 3 - 1) + dx;
            float y0f = floorf(py), x0f = floorf(pxf);
            int y0 = (int)y0f, x0 = (int)x0f;
            float ly = py - y0f, lx = pxf - x0f;
            bool vy0 = (y0 >= 0) && (y0 < 64);
            bool vy1 = (y0 >= -1) && (y0 < 63);
            bool vx0 = (x0 >= 0) && (x0 < 64);
            bool vx1 = (x0 >= -1) && (x0 < 63);
            float w00 = (1.f - ly) * (1.f - lx) * mv * ((vy0 && vx0) ? 1.f : 0.f);
            float w01 = (1.f - ly) * lx         * mv * ((vy0 && vx1) ? 1.f : 0.f);
            float w10 = ly         * (1.f - lx) * mv * ((vy1 && vx0) ? 1.f : 0.f);
            float w11 = ly         * lx         * mv * ((vy1 && vx1) ? 1.f : 0.f);
            int y0c = min(max(y0, 0), 63), y1c = min(max(y0 + 1, 0), 63);
            int bx = min(max(x0, 0), 62);      // aligned-ish pair window [bx, bx+1]
            s_po[p] = make_int2(y0c * 64 + bx, y1c * 64 + bx);
            float cA0, cB0, cA1, cB1;
            if (x0 == bx)          { cA0 = w00; cB0 = w01; cA1 = w10; cB1 = w11; }
            else if (x0 + 1 == bx) { cA0 = w01; cB0 = 0.f; cA1 = w11; cB1 = 0.f; }  // x0 == -1
            else if (x0 == bx + 1) { cA0 = 0.f; cB0 = w00; cA1 = 0.f; cB1 = w10; }  // x0 == 63
            else                   { cA0 = 0.f; cB0 = 0.f; cA1 = 0.f; cB1 = 0.f; }
            s_cw[p] = make_float4(cA0, cB0, cA1, cB1);
        } else {
            s_po[p] = make_int2(0, 0);
            s_cw[p] = make_float4(0.f, 0.f, 0.f, 0.f);
        }
    }

    const unsigned int* xpb = xpair + (size_t)b * CHI * 4096;
    const bf16x8* wBv = (const bf16x8*)wB;

    // build-role indices: thread covers kin = cg*2, cg*2+1 at pixel pxl
    int pxl = tid & 31, cg = tid >> 5;
    int tp  = cg >> 3;                  // tap within pair
    int cb2 = (cg & 7) * 2;             // channel base within 16-chunk

    f32x4 zf = {0.f, 0.f, 0.f, 0.f};
    f32x4 acc[4] = {zf, zf, zf, zf};

    unsigned int ta0, ua0, ta1, ua1;    // parity-0 pipeline slot
    unsigned int tb0, ub0, tb1, ub1;    // parity-1 pipeline slot

#define LOADS(s, T0, U0, T1, U1) do {                                   \
        int s_ = (s); int cc_ = s_ / 5; int tpr_ = s_ - cc_ * 5;        \
        int tap_ = tpr_ * 2 + tp;                                       \
        int2 oo_ = s_po[tap_ * 32 + pxl];                               \
        const unsigned int* xc_ = xpb + (size_t)(cc_ * 16 + cb2) * 4096;\
        T0 = xc_[oo_.x]; U0 = xc_[oo_.y];                               \
        T1 = xc_[4096 + oo_.x]; U1 = xc_[4096 + oo_.y];                 \
    } while (0)

#define WRITEA(s, T0, U0, T1, U1) do {                                  \
        int s_ = (s); int cc_ = s_ / 5; int tpr_ = s_ - cc_ * 5;        \
        int tap_ = tpr_ * 2 + tp;                                       \
        float4 cw_ = s_cw[tap_ * 32 + pxl];                             \
        float v0_ = cw_.x * bflo(T0) + cw_.y * bfhi(T0)                 \
                  + cw_.z * bflo(U0) + cw_.w * bfhi(U0);                \
        float v1_ = cw_.x * bflo(T1) + cw_.y * bfhi(T1)                 \
                  + cw_.z * bflo(U1) + cw_.w * bfhi(U1);                \
        unsigned int pk_ = (unsigned int)f2bf(v0_)                      \
                         | ((unsigned int)f2bf(v1_) << 16);             \
        *(unsigned int*)&sA[(s_) & 1][pxl * 40 + cg * 2] = pk_;         \
    } while (0)

    __syncthreads();   // metadata ready

    // pipeline prologue: loads for steps 0,1; step 0 written to buf0
    LOADS(0, ta0, ua0, ta1, ua1);
    LOADS(1, tb0, ub0, tb1, ub1);
    WRITEA(0, ta0, ua0, ta1, ua1);
    bf16x8 bf[4], nbf[4];
#pragma unroll
    for (int j = 0; j < 4; ++j)
        bf[j] = wBv[((size_t)(nb * 64 + j * 16 + ln)) * 4 + lk];
    __syncthreads();

    for (int kk = 0; kk < NSTEP; kk += 2) {
        {   // step kk (parity 0)
            bf16x8 af = *(const bf16x8*)&sA[0][(mt * 16 + ln) * 40 + lk * 8];
            if (kk + 2 < NSTEP) LOADS(kk + 2, ta0, ua0, ta1, ua1);
#pragma unroll
            for (int j = 0; j < 4; ++j)
                nbf[j] = wBv[((size_t)(kk + 1) * 256 + nb * 64 + j * 16 + ln) * 4 + lk];
            WRITEA(kk + 1, tb0, ub0, tb1, ub1);
#pragma unroll
            for (int j = 0; j < 4; ++j)
                acc[j] = __builtin_amdgcn_mfma_f32_16x16x32_bf16(af, bf[j], acc[j], 0, 0, 0);
#pragma unroll
            for (int j = 0; j < 4; ++j) bf[j] = nbf[j];
            __syncthreads();
        }
        {   // step kk+1 (parity 1)
            bf16x8 af = *(const bf16x8*)&sA[1][(mt * 16 + ln) * 40 + lk * 8];
            if (kk + 3 < NSTEP) LOADS(kk + 3, tb0, ub0, tb1, ub1);
            if (kk + 2 < NSTEP) {
#pragma unroll
                for (int j = 0; j < 4; ++j)
                    nbf[j] = wBv[((size_t)(kk + 2) * 256 + nb * 64 + j * 16 + ln) * 4 + lk];
                WRITEA(kk + 2, ta0, ua0, ta1, ua1);
            }
#pragma unroll
            for (int j = 0; j < 4; ++j)
                acc[j] = __builtin_amdgcn_mfma_f32_16x16x32_bf16(af, bf[j], acc[j], 0, 0, 0);
            if (kk + 2 < NSTEP) {
#pragma unroll
                for (int j = 0; j < 4; ++j) bf[j] = nbf[j];
            }
            __syncthreads();
        }
    }
#undef LOADS
#undef WRITEA

    // epilogue: bias + BN(eval) + ReLU, float4 stores
#pragma unroll
    for (int j = 0; j < 4; ++j) {
        int oc = nb * 64 + j * 16 + ln;
        float inv = gamma[oc] * rsqrtf(rvar[oc] + 1e-5f);
        float sh  = beta[oc] - rmean[oc] * inv + bias[oc] * inv;
        f32x4 a = acc[j];
        float4 r = make_float4(fmaxf(a.x * inv + sh, 0.f),
                               fmaxf(a.y * inv + sh, 0.f),
                               fmaxf(a.z * inv + sh, 0.f),
                               fmaxf(a.w * inv + sh, 0.f));
        size_t oi = (((size_t)b * 256 + oc) * 64 + h) * 64 + pxbase + mt * 16 + lk * 4;
        *(float4*)(out + oi) = r;
    }
}

extern "C" void kernel_launch(void* const* d_in, const int* in_sizes, int n_in,
                              void* d_out, int out_size, void* d_ws, size_t ws_size,
                              hipStream_t stream) {
    const float* x      = (const float*)d_in[0];
    const float* w_off  = (const float*)d_in[1];
    const float* b_off  = (const float*)d_in[2];
    const float* weight = (const float*)d_in[3];
    const float* bias   = (const float*)d_in[4];
    const float* gamma  = (const float*)d_in[5];
    const float* beta   = (const float*)d_in[6];
    const float* rmean  = (const float*)d_in[7];
    const float* rvar   = (const float*)d_in[8];
    float* out = (float*)d_out;

    float* ws    = (float*)d_ws;
    float* dyA   = ws;
    float* dxA   = dyA + N_OFF;
    float* maskA = dxA + N_OFF;                              // pre-sigmoid
    unsigned short* wB  = (unsigned short*)(maskA + N_OFF);  // 655360 bf16
    unsigned short* wOB = wB + 655360;                       // 73728 bf16
    unsigned int* xpair = (unsigned int*)(wOB + 73728);      // 4194304 uint

    hipLaunchKernelGGL(prep_all, dim3(2848 + 16384), dim3(256), 0, stream,
                       weight, w_off, x, wB, wOB, xpair);
    hipLaunchKernelGGL(offset_gemm_v6, dim3(256), dim3(512), 0, stream,
                       x, wOB, b_off, dyA, dxA, maskA);
    hipLaunchKernelGGL(dcn_main_v6, dim3(512), dim3(512), 0, stream,
                       xpair, dyA, dxA, maskA, wB, bias, gamma, beta, rmean, rvar, out);
}

// Round 7
// 201.155 us; speedup vs baseline: 5.7760x; 1.1498x over previous
//
#include <hip/hip_runtime.h>
#include <math.h>

#define NH 64
#define NW 64
#define NB 4
#define CHI 256
#define CHO 256

typedef __attribute__((ext_vector_type(8))) short bf16x8;   // 8 bf16 = 4 VGPR (MFMA A/B frag)
typedef __attribute__((ext_vector_type(4))) float f32x4;    // MFMA C/D frag

static __device__ __forceinline__ unsigned short f2bf(float f) {
    unsigned int u = __float_as_uint(f);
    u += 0x7fffu + ((u >> 16) & 1u);     // RNE
    return (unsigned short)(u >> 16);
}
static __device__ __forceinline__ float bflo(unsigned int p) { return __uint_as_float(p << 16); }
static __device__ __forceinline__ float bfhi(unsigned int p) { return __uint_as_float(p & 0xffff0000u); }

#define N_OFF (NB * 9 * NH * NW)   // 147456 per array

// ws layout:
//   dyA/dxA/maskA float [147456] each (maskA pre-sigmoid)
//   wB   bf16 [72][256 o][32 kin]   ks = cc*9+kt, kin = channel within 32-chunk cc
//   wOB  bf16 [72][32 oc][32 kin]   same K-order
//   xpair uint [B*CHI*4096]         (bf16(x[p]), bf16(x[p+1])) packed

__global__ __launch_bounds__(256) void prep_all(const float* __restrict__ weight,
                                                const float* __restrict__ w_off,
                                                const float* __restrict__ x,
                                                unsigned short* __restrict__ wB,
                                                unsigned short* __restrict__ wOB,
                                                unsigned int* __restrict__ xpair) {
    int bid = blockIdx.x, tid = threadIdx.x;
    if (bid < 2304) {
        int idx = bid * 256 + tid;             // < 589824
        int kin = idx & 31, o = (idx >> 5) & 255, ks = idx >> 13;
        int cc = ks / 9, kt = ks - cc * 9;
        int c = cc * 32 + kin;
        wB[idx] = f2bf(weight[((size_t)o * CHI + c) * 9 + kt]);
    } else if (bid < 2304 + 288) {
        int idx = (bid - 2304) * 256 + tid;    // < 73728
        int kin = idx & 31, oc = (idx >> 5) & 31, ks = idx >> 10;
        int cc = ks / 9, kt = ks - cc * 9;
        int c = cc * 32 + kin;
        wOB[idx] = (oc < 27) ? f2bf(w_off[((size_t)oc * CHI + c) * 9 + kt])
                             : (unsigned short)0;
    } else {
        int idx = (bid - 2592) * 256 + tid;    // < 4194304
        int w = idx & 63;
        float lo = x[idx];
        float hi = (w < 63) ? x[idx + 1] : 0.f;
        xpair[idx] = (unsigned int)f2bf(lo) | ((unsigned int)f2bf(hi) << 16);
    }
}

// ---- kernel 2: offset/mask conv via shifted LDS windows + MFMA, 4 blocks/CU ----
__global__ __launch_bounds__(256) void offset_gemm_v7(const float* __restrict__ x,
        const unsigned short* __restrict__ wOB, const float* __restrict__ b_off,
        float* __restrict__ dyA, float* __restrict__ dxA, float* __restrict__ maskA) {
    __shared__ unsigned short sX[3][34][40];   // [rw][pxp][ci pad40] 16320 B

    int id = blockIdx.x;                       // 512 blocks
    int xcd = id & 7, sl = id >> 3;            // sl 0..63
    int b = xcd >> 1;
    int h = (xcd & 1) * 32 + (sl & 31);
    int pxbase = (sl >> 5) * 32;

    int tid = threadIdx.x;
    int lane = tid & 63, q = tid >> 6;
    int ln = lane & 15, lk = lane >> 4;
    int mt = q & 1, nt = q >> 1;               // wave-tile: 16 px x 16 oc

    const bf16x8* wOBv = (const bf16x8*)wOB;

    f32x4 acc = {0.f, 0.f, 0.f, 0.f};
    bf16x8 bf = wOBv[((size_t)(nt * 16 + ln)) * 4 + lk];   // slice 0
    bf16x8 nbf;

    for (int cc = 0; cc < 8; ++cc) {
        __syncthreads();   // prior phase reads done
        // stage rows h-1..h+1, px window [pxbase-1, pxbase+32], 32 ch, fp32 -> bf16
        for (int e = tid; e < 1632; e += 256) {   // 3*34*16 channel-pairs
            int px_i = e % 34;
            int t = e / 34;                       // 0..47
            int rw = t % 3, ci2 = t / 3;          // ci2 0..15
            int y = h + rw - 1;
            int pxw = pxbase + px_i - 1;
            float v0 = 0.f, v1 = 0.f;
            if (y >= 0 && y < 64 && pxw >= 0 && pxw < 64) {
                const float* base = x + (((size_t)b * CHI + cc * 32 + ci2 * 2) * 64 + y) * 64 + pxw;
                v0 = base[0];
                v1 = base[4096];
            }
            *(unsigned int*)&sX[rw][px_i][ci2 * 2] =
                (unsigned int)f2bf(v0) | ((unsigned int)f2bf(v1) << 16);
        }
        __syncthreads();
#pragma unroll
        for (int kt = 0; kt < 9; ++kt) {
            int s = cc * 9 + kt;
            int rw = kt / 3, dxc = kt % 3 - 1;
            int pxp = 1 + mt * 16 + ln + dxc;     // 0..33
            bf16x8 af = *(const bf16x8*)&sX[rw][pxp][lk * 8];
            bool more = (s + 1 < 72);
            if (more) nbf = wOBv[((size_t)(s + 1) * 32 + nt * 16 + ln) * 4 + lk];
            acc = __builtin_amdgcn_mfma_f32_16x16x32_bf16(af, bf, acc, 0, 0, 0);
            if (more) bf = nbf;
        }
    }

    int oc = nt * 16 + ln;
    if (oc < 27) {
        int arr = oc / 9, k9 = oc - arr * 9;
        float* dst = (arr == 0) ? dyA : (arr == 1) ? dxA : maskA;
        float bb = b_off[oc];
#pragma unroll
        for (int r = 0; r < 4; ++r) {
            int px = pxbase + mt * 16 + lk * 4 + r;
            dst[((b * 9 + k9) * 64 + h) * 64 + px] = acc[r] + bb;
        }
    }
}

// ---- kernel 3: deformable sampling + MFMA GEMM, K-split waves, 4-slice phases ----
__global__ __launch_bounds__(512) void dcn_main_v7(
        const unsigned int* __restrict__ xpair,
        const float* __restrict__ dyA, const float* __restrict__ dxA,
        const float* __restrict__ maskA, const unsigned short* __restrict__ wB,
        const float* __restrict__ bias, const float* __restrict__ gamma,
        const float* __restrict__ beta, const float* __restrict__ rmean,
        const float* __restrict__ rvar, float* __restrict__ out) {
    __shared__ int2   s_po[288];                // 9 taps x 32 px
    __shared__ float4 s_cw[288];
    __shared__ unsigned short sA[8][32 * 40];   // 8 slice-buffers, pad 40 (16B-aligned rows)
    __shared__ float sOut[32][260];             // kh-combine, padded stride

    int id = blockIdx.x;                        // 512 blocks
    int xcd = id & 7, sl = id >> 3;
    int b = xcd >> 1;
    int h = (xcd & 1) * 32 + (sl & 31);
    int pxbase = (sl >> 5) * 32;

    int tid = threadIdx.x;
    int lane = tid & 63, q = tid >> 6;
    int ln = lane & 15, lk = lane >> 4;
    int nb = q & 3, kh = q >> 2;                // wave -> (64-oc group, K-half)

    // phase 0: bilinear metadata per (tap, px); sigmoid applied here
    for (int p = tid; p < 288; p += 512) {
        int k = p >> 5, pwl = p & 31, pw = pxbase + pwl;
        int ii = ((b * 9 + k) * 64 + h) * 64 + pw;
        float dy = dyA[ii], dx = dxA[ii];
        float mv = 1.f / (1.f + __expf(-maskA[ii]));
        float py  = (float)h  + (float)(k / 3 - 1) + dy;
        float pxf = (float)pw + (float)(k % 3 - 1) + dx;
        float y0f = floorf(py), x0f = floorf(pxf);
        int y0 = (int)y0f, x0 = (int)x0f;
        float ly = py - y0f, lx = pxf - x0f;
        bool vy0 = (y0 >= 0) && (y0 < 64);
        bool vy1 = (y0 >= -1) && (y0 < 63);
        bool vx0 = (x0 >= 0) && (x0 < 64);
        bool vx1 = (x0 >= -1) && (x0 < 63);
        float w00 = (1.f - ly) * (1.f - lx) * mv * ((vy0 && vx0) ? 1.f : 0.f);
        float w01 = (1.f - ly) * lx         * mv * ((vy0 && vx1) ? 1.f : 0.f);
        float w10 = ly         * (1.f - lx) * mv * ((vy1 && vx0) ? 1.f : 0.f);
        float w11 = ly         * lx         * mv * ((vy1 && vx1) ? 1.f : 0.f);
        int y0c = min(max(y0, 0), 63), y1c = min(max(y0 + 1, 0), 63);
        int bx = min(max(x0, 0), 62);           // pair window [bx, bx+1]
        s_po[p] = make_int2(y0c * 64 + bx, y1c * 64 + bx);
        float cA0, cB0, cA1, cB1;
        if (x0 == bx)          { cA0 = w00; cB0 = w01; cA1 = w10; cB1 = w11; }
        else if (x0 + 1 == bx) { cA0 = w01; cB0 = 0.f; cA1 = w11; cB1 = 0.f; }  // x0 == -1
        else if (x0 == bx + 1) { cA0 = 0.f; cB0 = w00; cA1 = 0.f; cB1 = w10; }  // x0 == 63
        else                   { cA0 = 0.f; cB0 = 0.f; cA1 = 0.f; cB1 = 0.f; }
        s_cw[p] = make_float4(cA0, cB0, cA1, cB1);
    }

    int pxl = tid & 31, cg = tid >> 5;          // build role: kin = cg*2, cg*2+1
    const unsigned int* xpb = xpair + (size_t)b * CHI * 4096;
    const bf16x8* wBv = (const bf16x8*)wB;

    f32x4 zf = {0.f, 0.f, 0.f, 0.f};
    f32x4 acc[2][4] = {{zf, zf, zf, zf}, {zf, zf, zf, zf}};

    unsigned int R[16];

#define LOADS1(s, r0) do { int s_ = (s); int cc_ = s_ / 9;                    \
        int kt_ = s_ - cc_ * 9;                                               \
        int2 oo_ = s_po[kt_ * 32 + pxl];                                      \
        const unsigned int* xc_ = xpb + (size_t)(cc_ * 32 + cg * 2) * 4096;   \
        R[(r0) + 0] = xc_[oo_.x];        R[(r0) + 1] = xc_[oo_.y];            \
        R[(r0) + 2] = xc_[4096 + oo_.x]; R[(r0) + 3] = xc_[4096 + oo_.y];     \
    } while (0)

#define WRITEA1(s, buf, r0) do { int s_ = (s); int kt_ = s_ - (s_ / 9) * 9;   \
        float4 cw_ = s_cw[kt_ * 32 + pxl];                                    \
        float v0_ = cw_.x * bflo(R[(r0)])     + cw_.y * bfhi(R[(r0)])         \
                  + cw_.z * bflo(R[(r0) + 1]) + cw_.w * bfhi(R[(r0) + 1]);    \
        float v1_ = cw_.x * bflo(R[(r0) + 2]) + cw_.y * bfhi(R[(r0) + 2])     \
                  + cw_.z * bflo(R[(r0) + 3]) + cw_.w * bfhi(R[(r0) + 3]);    \
        *(unsigned int*)&sA[buf][pxl * 40 + cg * 2] =                         \
            (unsigned int)f2bf(v0_) | ((unsigned int)f2bf(v1_) << 16);        \
    } while (0)

#define LOADS4(g) do { int g_ = (g);                                          \
        LOADS1(2 * g_, 0);      LOADS1(2 * g_ + 1, 4);                        \
        LOADS1(36 + 2 * g_, 8); LOADS1(37 + 2 * g_, 12); } while (0)

#define WRITEA4(g) do { int g_ = (g); int bb_ = (g_ & 1) * 4;                 \
        WRITEA1(2 * g_, bb_ + 0, 0);      WRITEA1(2 * g_ + 1, bb_ + 1, 4);    \
        WRITEA1(36 + 2 * g_, bb_ + 2, 8); WRITEA1(37 + 2 * g_, bb_ + 3, 12);  \
    } while (0)

    __syncthreads();   // metadata ready

    // software pipeline prologue
    LOADS4(0);
    WRITEA4(0);
    LOADS4(1);
    bf16x8 bf[4], nbf[4];
#pragma unroll
    for (int j = 0; j < 4; ++j)
        bf[j] = wBv[((size_t)(kh * 36) * 256 + nb * 64 + j * 16 + ln) * 4 + lk];
    __syncthreads();

    for (int g = 0; g < 18; ++g) {
        if (g + 1 < 18) WRITEA4(g + 1);         // regs from phase g-1 (drained at barrier)
        if (g + 2 < 18) LOADS4(g + 2);          // issue early; drained at end-of-phase barrier
#pragma unroll
        for (int i = 0; i < 2; ++i) {           // consume this wave's 2 slices
            int off = 2 * g + i;                // 0..35 within K-half
            int buf = (g & 1) * 4 + kh * 2 + i;
            bf16x8 af0 = *(const bf16x8*)&sA[buf][ln * 40 + lk * 8];
            bf16x8 af1 = *(const bf16x8*)&sA[buf][(16 + ln) * 40 + lk * 8];
            bool more = (off + 1 < 36);
            if (more) {
                int sn = kh * 36 + off + 1;
#pragma unroll
                for (int j = 0; j < 4; ++j)
                    nbf[j] = wBv[((size_t)sn * 256 + nb * 64 + j * 16 + ln) * 4 + lk];
            }
#pragma unroll
            for (int j = 0; j < 4; ++j) {
                acc[0][j] = __builtin_amdgcn_mfma_f32_16x16x32_bf16(af0, bf[j], acc[0][j], 0, 0, 0);
                acc[1][j] = __builtin_amdgcn_mfma_f32_16x16x32_bf16(af1, bf[j], acc[1][j], 0, 0, 0);
            }
            if (more) {
#pragma unroll
                for (int j = 0; j < 4; ++j) bf[j] = nbf[j];
            }
        }
        __syncthreads();
    }
#undef LOADS1
#undef WRITEA1
#undef LOADS4
#undef WRITEA4

    // kh-combine + BN + ReLU epilogue
    if (kh == 1) {
#pragma unroll
        for (int m = 0; m < 2; ++m)
#pragma unroll
            for (int j = 0; j < 4; ++j) {
                int oc = nb * 64 + j * 16 + ln;
#pragma unroll
                for (int r = 0; r < 4; ++r)
                    sOut[m * 16 + lk * 4 + r][oc] = acc[m][j][r];
            }
    }
    __syncthreads();
    if (kh == 0) {
#pragma unroll
        for (int m = 0; m < 2; ++m)
#pragma unroll
            for (int j = 0; j < 4; ++j) {
                int oc = nb * 64 + j * 16 + ln;
                float inv = gamma[oc] * rsqrtf(rvar[oc] + 1e-5f);
                float sh  = beta[oc] - rmean[oc] * inv + bias[oc] * inv;
                int row = m * 16 + lk * 4;
                float4 rr;
                rr.x = fmaxf((acc[m][j][0] + sOut[row + 0][oc]) * inv + sh, 0.f);
                rr.y = fmaxf((acc[m][j][1] + sOut[row + 1][oc]) * inv + sh, 0.f);
                rr.z = fmaxf((acc[m][j][2] + sOut[row + 2][oc]) * inv + sh, 0.f);
                rr.w = fmaxf((acc[m][j][3] + sOut[row + 3][oc]) * inv + sh, 0.f);
                size_t oi = (((size_t)b * 256 + oc) * 64 + h) * 64 + pxbase + row;
                *(float4*)(out + oi) = rr;
            }
    }
}

extern "C" void kernel_launch(void* const* d_in, const int* in_sizes, int n_in,
                              void* d_out, int out_size, void* d_ws, size_t ws_size,
                              hipStream_t stream) {
    const float* x      = (const float*)d_in[0];
    const float* w_off  = (const float*)d_in[1];
    const float* b_off  = (const float*)d_in[2];
    const float* weight = (const float*)d_in[3];
    const float* bias   = (const float*)d_in[4];
    const float* gamma  = (const float*)d_in[5];
    const float* beta   = (const float*)d_in[6];
    const float* rmean  = (const float*)d_in[7];
    const float* rvar   = (const float*)d_in[8];
    float* out = (float*)d_out;

    float* ws    = (float*)d_ws;
    float* dyA   = ws;
    float* dxA   = dyA + N_OFF;
    float* maskA = dxA + N_OFF;                              // pre-sigmoid
    unsigned short* wB  = (unsigned short*)(maskA + N_OFF);  // 589824 bf16
    unsigned short* wOB = wB + 589824;                       // 73728 bf16
    unsigned int* xpair = (unsigned int*)(wOB + 73728);      // 4194304 uint

    hipLaunchKernelGGL(prep_all, dim3(2592 + 16384), dim3(256), 0, stream,
                       weight, w_off, x, wB, wOB, xpair);
    hipLaunchKernelGGL(offset_gemm_v7, dim3(512), dim3(256), 0, stream,
                       x, wOB, b_off, dyA, dxA, maskA);
    hipLaunchKernelGGL(dcn_main_v7, dim3(512), dim3(512), 0, stream,
                       xpair, dyA, dxA, maskA, wB, bias, gamma, beta, rmean, rvar, out);
}

// Round 8
// 182.694 us; speedup vs baseline: 6.3596x; 1.1010x over previous
//
#include <hip/hip_runtime.h>
#include <math.h>

#define NH 64
#define NW 64
#define NB 4
#define CHI 256
#define CHO 256
#define XT_B (66 * 66 * 256)   // per-batch xT elements (zero-padded 66x66, ch-inner)

typedef __attribute__((ext_vector_type(8))) short bf16x8;   // MFMA A/B frag (4 VGPR)
typedef __attribute__((ext_vector_type(4))) float f32x4;    // MFMA C/D frag

static __device__ __forceinline__ unsigned short f2bf(float f) {
    unsigned int u = __float_as_uint(f);
    u += 0x7fffu + ((u >> 16) & 1u);     // RNE
    return (unsigned short)(u >> 16);
}
static __device__ __forceinline__ float bflo(unsigned int p) { return __uint_as_float(p << 16); }
static __device__ __forceinline__ float bfhi(unsigned int p) { return __uint_as_float(p & 0xffff0000u); }
static __device__ __forceinline__ unsigned int pkbf(float a, float b) {
    return (unsigned int)f2bf(a) | ((unsigned int)f2bf(b) << 16);
}

#define N_OFF (NB * 9 * NH * NW)   // 147456 per array

// ws layout:
//   dyA/dxA/maskA float [147456] each
//   wB   bf16 [72][256 o][32 kin]   ks = cc*9+kt, kin = channel within 32-chunk cc
//   wOB  bf16 [72][32 oc][32 kin]
//   xT   bf16 [B][66 yp][66 xp][256 c]  zero halo at yp/xp = 0,65 (memset by host launch)

__global__ __launch_bounds__(256) void prep_all(const float* __restrict__ weight,
                                                const float* __restrict__ w_off,
                                                const float* __restrict__ x,
                                                unsigned short* __restrict__ wB,
                                                unsigned short* __restrict__ wOB,
                                                unsigned short* __restrict__ xT) {
    __shared__ unsigned short sT[64 * 266];
    int bid = blockIdx.x, tid = threadIdx.x;
    if (bid < 2304) {
        int idx = bid * 256 + tid;             // < 589824
        int kin = idx & 31, o = (idx >> 5) & 255, ks = idx >> 13;
        int cc = ks / 9, kt = ks - cc * 9;
        int c = cc * 32 + kin;
        wB[idx] = f2bf(weight[((size_t)o * CHI + c) * 9 + kt]);
    } else if (bid < 2304 + 288) {
        int idx = (bid - 2304) * 256 + tid;    // < 73728
        int kin = idx & 31, oc = (idx >> 5) & 31, ks = idx >> 10;
        int cc = ks / 9, kt = ks - cc * 9;
        int c = cc * 32 + kin;
        wOB[idx] = (oc < 27) ? f2bf(w_off[((size_t)oc * CHI + c) * 9 + kt])
                             : (unsigned short)0;
    } else {
        // transpose one (b, y) row-plane: x[b][c][y][*] f32 -> xT[b][y+1][*+1][c] bf16
        int bid2 = bid - 2592;                 // 0..255
        int b = bid2 >> 6, y = bid2 & 63;
        for (int rep = 0; rep < 16; ++rep) {
            int idx = rep * 256 + tid;         // 0..4095
            int c = idx >> 4, p4 = (idx & 15) * 4;
            const float* src = x + (((size_t)b * CHI + c) * 64 + y) * 64 + p4;
            float4 v = *(const float4*)src;
            sT[(p4 + 0) * 266 + c] = f2bf(v.x);
            sT[(p4 + 1) * 266 + c] = f2bf(v.y);
            sT[(p4 + 2) * 266 + c] = f2bf(v.z);
            sT[(p4 + 3) * 266 + c] = f2bf(v.w);
        }
        __syncthreads();
        unsigned int* dst = (unsigned int*)(xT + ((size_t)(b * 66 + y + 1) * 66 + 1) * 256);
        for (int rep = 0; rep < 32; ++rep) {
            int idx = rep * 256 + tid;         // 0..8191
            int px = idx >> 7, cu = idx & 127;
            unsigned int lo = sT[px * 266 + cu * 2];
            unsigned int hi = sT[px * 266 + cu * 2 + 1];
            dst[(size_t)px * 128 + cu] = lo | (hi << 16);
        }
    }
}

// ---- kernel 2: offset/mask conv, barrier-free: A-frags loaded per-lane from xT ----
__global__ __launch_bounds__(256) void offset_gemm_v8(const unsigned short* __restrict__ xT,
        const unsigned short* __restrict__ wOB, const float* __restrict__ b_off,
        float* __restrict__ dyA, float* __restrict__ dxA, float* __restrict__ maskA) {
    int id = blockIdx.x;                       // 512 blocks
    int xcd = id & 7, sl = id >> 3;            // sl 0..63
    int b = xcd >> 1;
    int h = (xcd & 1) * 32 + (sl & 31);
    int pxbase = (sl >> 5) * 32;

    int tid = threadIdx.x;
    int lane = tid & 63, q = tid >> 6;
    int ln = lane & 15, lk = lane >> 4;
    int mt = q & 1, nt = q >> 1;               // wave-tile 16px x 16oc, full K

    const unsigned short* xTb = xT + (size_t)b * XT_B;
    const bf16x8* wOBv = (const bf16x8*)wOB;

    int px = pxbase + mt * 16 + ln;
    int posbase = (h + 1) * 66 + (px + 1);     // integer tap center in padded coords

    f32x4 acc = {0.f, 0.f, 0.f, 0.f};
    for (int cc = 0; cc < 8; ++cc) {
#pragma unroll
        for (int kt = 0; kt < 9; ++kt) {
            int s = cc * 9 + kt;
            int pos = posbase + (kt / 3 - 1) * 66 + (kt % 3 - 1);
            bf16x8 af = *(const bf16x8*)&xTb[(size_t)pos * 256 + cc * 32 + lk * 8];
            bf16x8 bf = wOBv[((size_t)s * 32 + nt * 16 + ln) * 4 + lk];
            acc = __builtin_amdgcn_mfma_f32_16x16x32_bf16(af, bf, acc, 0, 0, 0);
        }
    }

    int oc = nt * 16 + ln;
    if (oc < 27) {
        int arr = oc / 9, k9 = oc - arr * 9;
        float* dst = (arr == 0) ? dyA : (arr == 1) ? dxA : maskA;
        float bb = b_off[oc];
#pragma unroll
        for (int r = 0; r < 4; ++r) {
            int pxo = pxbase + mt * 16 + lk * 4 + r;
            dst[((b * 9 + k9) * 64 + h) * 64 + pxo] = acc[r] + bb;
        }
    }
}

// ---- kernel 3: deformable sampling (8ch/16B corner loads) + MFMA GEMM + BN + ReLU ----
__global__ __launch_bounds__(512) void dcn_main_v8(
        const unsigned short* __restrict__ xT,
        const float* __restrict__ dyA, const float* __restrict__ dxA,
        const float* __restrict__ maskA, const unsigned short* __restrict__ wB,
        const float* __restrict__ bias, const float* __restrict__ gamma,
        const float* __restrict__ beta, const float* __restrict__ rmean,
        const float* __restrict__ rvar, float* __restrict__ out) {
    // union'd LDS: K-phase {s_po, s_cw, sA} then epilogue sOut
    __shared__ __align__(16) unsigned char smem[33280];
    int4*   s_po = (int4*)smem;                                 // [288] corner offsets
    float4* s_cw = (float4*)(smem + 4608);                      // [288] bilinear weights
    unsigned short* sA = (unsigned short*)(smem + 9216);        // [8][32*40] slice bufs
    float (*sOut)[260] = (float(*)[260])smem;                   // epilogue kh-combine

    int id = blockIdx.x;                        // 512 blocks
    int xcd = id & 7, sl = id >> 3;
    int b = xcd >> 1;
    int h = (xcd & 1) * 32 + (sl & 31);
    int pxbase = (sl >> 5) * 32;

    int tid = threadIdx.x;
    int lane = tid & 63, q = tid >> 6;
    int ln = lane & 15, lk = lane >> 4;
    int nb = q & 3, kh = q >> 2;                // consumer: (64-oc group, K-half)

    // phase 0: bilinear metadata; zero-halo makes validity masks unnecessary
    for (int p = tid; p < 288; p += 512) {
        int k = p >> 5, pwl = p & 31, pw = pxbase + pwl;
        int ii = ((b * 9 + k) * 64 + h) * 64 + pw;
        float dy = dyA[ii], dx = dxA[ii];
        float mv = 1.f / (1.f + __expf(-maskA[ii]));
        float py  = (float)h  + (float)(k / 3 - 1) + dy;
        float pxf = (float)pw + (float)(k % 3 - 1) + dx;
        float y0f = floorf(py), x0f = floorf(pxf);
        int y0 = (int)y0f, x0 = (int)x0f;
        float ly = py - y0f, lx = pxf - x0f;
        int y0c = min(max(y0, -1), 64), y1c = min(max(y0 + 1, -1), 64);
        int x0c = min(max(x0, -1), 64), x1c = min(max(x0 + 1, -1), 64);
        int ry0 = (y0c + 1) * 66, ry1 = (y1c + 1) * 66;
        s_po[p] = make_int4(ry0 + x0c + 1, ry0 + x1c + 1, ry1 + x0c + 1, ry1 + x1c + 1);
        s_cw[p] = make_float4((1.f - ly) * (1.f - lx) * mv, (1.f - ly) * lx * mv,
                              ly * (1.f - lx) * mv,         ly * lx * mv);
    }

    // producer role: thread covers slice-slot sl4, 8 channels cg8*8.., pixel pxl
    int pxl = tid & 31, cg8 = (tid >> 5) & 3, sl4 = tid >> 7;
    int khp = sl4 >> 1, ip = sl4 & 1;           // producer slice = khp*36 + 2*phase + ip
    const unsigned short* xTb = xT + (size_t)b * XT_B + cg8 * 8;
    const bf16x8* wBv = (const bf16x8*)wB;

    f32x4 zf = {0.f, 0.f, 0.f, 0.f};
    f32x4 acc[2][4] = {{zf, zf, zf, zf}, {zf, zf, zf, zf}};

    uint4 C00, C01, C10, C11;

#define LOADS(s) do { int s_ = (s); int cc_ = s_ / 9; int kt_ = s_ - cc_ * 9;  \
        int4 o4_ = s_po[kt_ * 32 + pxl];                                       \
        const unsigned short* cb_ = xTb + cc_ * 32;                            \
        C00 = *(const uint4*)(cb_ + (size_t)o4_.x * 256);                      \
        C01 = *(const uint4*)(cb_ + (size_t)o4_.y * 256);                      \
        C10 = *(const uint4*)(cb_ + (size_t)o4_.z * 256);                      \
        C11 = *(const uint4*)(cb_ + (size_t)o4_.w * 256);                      \
    } while (0)

#define WRITEA(s, buf) do { int s_ = (s); int kt_ = s_ - (s_ / 9) * 9;         \
        float4 w_ = s_cw[kt_ * 32 + pxl];                                      \
        uint4 pk_;                                                             \
        pk_.x = pkbf(w_.x*bflo(C00.x)+w_.y*bflo(C01.x)+w_.z*bflo(C10.x)+w_.w*bflo(C11.x), \
                     w_.x*bfhi(C00.x)+w_.y*bfhi(C01.x)+w_.z*bfhi(C10.x)+w_.w*bfhi(C11.x)); \
        pk_.y = pkbf(w_.x*bflo(C00.y)+w_.y*bflo(C01.y)+w_.z*bflo(C10.y)+w_.w*bflo(C11.y), \
                     w_.x*bfhi(C00.y)+w_.y*bfhi(C01.y)+w_.z*bfhi(C10.y)+w_.w*bfhi(C11.y)); \
        pk_.z = pkbf(w_.x*bflo(C00.z)+w_.y*bflo(C01.z)+w_.z*bflo(C10.z)+w_.w*bflo(C11.z), \
                     w_.x*bfhi(C00.z)+w_.y*bfhi(C01.z)+w_.z*bfhi(C10.z)+w_.w*bfhi(C11.z)); \
        pk_.w = pkbf(w_.x*bflo(C00.w)+w_.y*bflo(C01.w)+w_.z*bflo(C10.w)+w_.w*bflo(C11.w), \
                     w_.x*bfhi(C00.w)+w_.y*bfhi(C01.w)+w_.z*bfhi(C10.w)+w_.w*bfhi(C11.w)); \
        *(uint4*)&sA[(buf) * 1280 + pxl * 40 + cg8 * 8] = pk_;                 \
    } while (0)

    __syncthreads();   // metadata ready

    // software pipeline prologue
    LOADS(khp * 36 + ip);
    WRITEA(khp * 36 + ip, sl4);
    LOADS(khp * 36 + 2 + ip);
    bf16x8 bf[4], nbf[4];
#pragma unroll
    for (int j = 0; j < 4; ++j)
        bf[j] = wBv[((size_t)(kh * 36) * 256 + nb * 64 + j * 16 + ln) * 4 + lk];
    __syncthreads();

    for (int g = 0; g < 18; ++g) {
        if (g + 1 < 18) WRITEA(khp * 36 + 2 * (g + 1) + ip, ((g + 1) & 1) * 4 + sl4);
        if (g + 2 < 18) LOADS(khp * 36 + 2 * (g + 2) + ip);
#pragma unroll
        for (int i = 0; i < 2; ++i) {           // consume this wave's 2 slices
            int off = 2 * g + i;                // 0..35 within K-half
            int buf = (g & 1) * 4 + kh * 2 + i;
            bf16x8 af0 = *(const bf16x8*)&sA[buf * 1280 + ln * 40 + lk * 8];
            bf16x8 af1 = *(const bf16x8*)&sA[buf * 1280 + (16 + ln) * 40 + lk * 8];
            bool more = (off + 1 < 36);
            if (more) {
                int sn = kh * 36 + off + 1;
#pragma unroll
                for (int j = 0; j < 4; ++j)
                    nbf[j] = wBv[((size_t)sn * 256 + nb * 64 + j * 16 + ln) * 4 + lk];
            }
#pragma unroll
            for (int j = 0; j < 4; ++j) {
                acc[0][j] = __builtin_amdgcn_mfma_f32_16x16x32_bf16(af0, bf[j], acc[0][j], 0, 0, 0);
                acc[1][j] = __builtin_amdgcn_mfma_f32_16x16x32_bf16(af1, bf[j], acc[1][j], 0, 0, 0);
            }
            if (more) {
#pragma unroll
                for (int j = 0; j < 4; ++j) bf[j] = nbf[j];
            }
        }
        __syncthreads();
    }
#undef LOADS
#undef WRITEA

    // kh-combine + BN + ReLU epilogue (sOut aliases the K-phase LDS; last barrier done)
    if (kh == 1) {
#pragma unroll
        for (int m = 0; m < 2; ++m)
#pragma unroll
            for (int j = 0; j < 4; ++j) {
                int oc = nb * 64 + j * 16 + ln;
#pragma unroll
                for (int r = 0; r < 4; ++r)
                    sOut[m * 16 + lk * 4 + r][oc] = acc[m][j][r];
            }
    }
    __syncthreads();
    if (kh == 0) {
#pragma unroll
        for (int m = 0; m < 2; ++m)
#pragma unroll
            for (int j = 0; j < 4; ++j) {
                int oc = nb * 64 + j * 16 + ln;
                float inv = gamma[oc] * rsqrtf(rvar[oc] + 1e-5f);
                float sh  = beta[oc] - rmean[oc] * inv + bias[oc] * inv;
                int row = m * 16 + lk * 4;
                float4 rr;
                rr.x = fmaxf((acc[m][j][0] + sOut[row + 0][oc]) * inv + sh, 0.f);
                rr.y = fmaxf((acc[m][j][1] + sOut[row + 1][oc]) * inv + sh, 0.f);
                rr.z = fmaxf((acc[m][j][2] + sOut[row + 2][oc]) * inv + sh, 0.f);
                rr.w = fmaxf((acc[m][j][3] + sOut[row + 3][oc]) * inv + sh, 0.f);
                size_t oi = (((size_t)b * 256 + oc) * 64 + h) * 64 + pxbase + row;
                *(float4*)(out + oi) = rr;
            }
    }
}

extern "C" void kernel_launch(void* const* d_in, const int* in_sizes, int n_in,
                              void* d_out, int out_size, void* d_ws, size_t ws_size,
                              hipStream_t stream) {
    const float* x      = (const float*)d_in[0];
    const float* w_off  = (const float*)d_in[1];
    const float* b_off  = (const float*)d_in[2];
    const float* weight = (const float*)d_in[3];
    const float* bias   = (const float*)d_in[4];
    const float* gamma  = (const float*)d_in[5];
    const float* beta   = (const float*)d_in[6];
    const float* rmean  = (const float*)d_in[7];
    const float* rvar   = (const float*)d_in[8];
    float* out = (float*)d_out;

    float* ws    = (float*)d_ws;
    float* dyA   = ws;
    float* dxA   = dyA + N_OFF;
    float* maskA = dxA + N_OFF;                              // pre-sigmoid
    unsigned short* wB  = (unsigned short*)(maskA + N_OFF);  // 589824 bf16
    unsigned short* wOB = wB + 589824;                       // 73728 bf16
    unsigned short* xT  = wOB + 73728;                       // 4 * 66*66*256 bf16

    hipMemsetAsync(xT, 0, (size_t)NB * XT_B * sizeof(unsigned short), stream);
    hipLaunchKernelGGL(prep_all, dim3(2592 + 256), dim3(256), 0, stream,
                       weight, w_off, x, wB, wOB, xT);
    hipLaunchKernelGGL(offset_gemm_v8, dim3(512), dim3(256), 0, stream,
                       xT, wOB, b_off, dyA, dxA, maskA);
    hipLaunchKernelGGL(dcn_main_v8, dim3(512), dim3(512), 0, stream,
                       xT, dyA, dxA, maskA, wB, bias, gamma, beta, rmean, rvar, out);
}

// Round 9
// 176.939 us; speedup vs baseline: 6.5664x; 1.0325x over previous
//
#include <hip/hip_runtime.h>
#include <math.h>

#define NH 64
#define NW 64
#define NB 4
#define CHI 256
#define CHO 256
#define XT_B (66 * 66 * 256)   // per-batch xT elements (zero-padded 66x66, ch-inner)

typedef __attribute__((ext_vector_type(8))) short bf16x8;   // MFMA A/B frag (4 VGPR)
typedef __attribute__((ext_vector_type(4))) float f32x4;    // MFMA C/D frag

static __device__ __forceinline__ unsigned short f2bf(float f) {
    unsigned int u = __float_as_uint(f);
    u += 0x7fffu + ((u >> 16) & 1u);     // RNE
    return (unsigned short)(u >> 16);
}
static __device__ __forceinline__ float bflo(unsigned int p) { return __uint_as_float(p << 16); }
static __device__ __forceinline__ float bfhi(unsigned int p) { return __uint_as_float(p & 0xffff0000u); }
static __device__ __forceinline__ unsigned int pkbf(float a, float b) {
    return (unsigned int)f2bf(a) | ((unsigned int)f2bf(b) << 16);
}

// ws layout:
//   wB   bf16 [72][256 o][32 kin]   ks = cc*9+kt, kin = channel within 32-chunk cc
//   wOB  bf16 [72][32 oc][32 kin]
//   xT   bf16 [B][66 yp][66 xp][256 c]  zero halo at yp/xp = 0,65 (halo blocks in prep)

// grid: [0,2304) wB pack | [2304,2592) wOB pack | [2592,3104) transpose | [3104,3624) halo zero
__global__ __launch_bounds__(256) void prep_all(const float* __restrict__ weight,
                                                const float* __restrict__ w_off,
                                                const float* __restrict__ x,
                                                unsigned short* __restrict__ wB,
                                                unsigned short* __restrict__ wOB,
                                                unsigned short* __restrict__ xT) {
    __shared__ unsigned short sT[64 * 134];
    int bid = blockIdx.x, tid = threadIdx.x;
    if (bid < 2304) {
        int idx = bid * 256 + tid;             // < 589824
        int kin = idx & 31, o = (idx >> 5) & 255, ks = idx >> 13;
        int cc = ks / 9, kt = ks - cc * 9;
        int c = cc * 32 + kin;
        wB[idx] = f2bf(weight[((size_t)o * CHI + c) * 9 + kt]);
    } else if (bid < 2592) {
        int idx = (bid - 2304) * 256 + tid;    // < 73728
        int kin = idx & 31, oc = (idx >> 5) & 31, ks = idx >> 10;
        int cc = ks / 9, kt = ks - cc * 9;
        int c = cc * 32 + kin;
        wOB[idx] = (oc < 27) ? f2bf(w_off[((size_t)oc * CHI + c) * 9 + kt])
                             : (unsigned short)0;
    } else if (bid < 3104) {
        // transpose half a (b,y) row-plane: x[b][c0..c0+128][y][*] f32 -> xT[b][y+1][*+1][c] bf16
        int bid2 = bid - 2592;                 // 0..511  (2 blocks/CU)
        int b = bid2 >> 7, rem = bid2 & 127;
        int y = rem >> 1, chalf = rem & 1;
        int c0 = chalf * 128;
        for (int rep = 0; rep < 8; ++rep) {
            int idx = rep * 256 + tid;         // 0..2047
            int c = idx >> 4, p4 = (idx & 15) * 4;
            const float* src = x + (((size_t)b * CHI + c0 + c) * 64 + y) * 64 + p4;
            float4 v = *(const float4*)src;
            sT[(p4 + 0) * 134 + c] = f2bf(v.x);
            sT[(p4 + 1) * 134 + c] = f2bf(v.y);
            sT[(p4 + 2) * 134 + c] = f2bf(v.z);
            sT[(p4 + 3) * 134 + c] = f2bf(v.w);
        }
        __syncthreads();
        unsigned int* dst = (unsigned int*)(xT + ((size_t)(b * 66 + y + 1) * 66 + 1) * 256)
                          + chalf * 64;
        for (int rep = 0; rep < 16; ++rep) {
            int idx = rep * 256 + tid;         // 0..4095
            int px = idx >> 6, cu = idx & 63;
            unsigned int lo = sT[px * 134 + cu * 2];
            unsigned int hi = sT[px * 134 + cu * 2 + 1];
            dst[(size_t)px * 128 + cu] = lo | (hi << 16);
        }
    } else {
        // zero the xT halo (rows y=0,65; cols x=0,65) -- ws is poisoned before each call
        int flat = (bid - 3104) * 256 + tid;   // 0..133119 uints
        int b = flat / 33280, r = flat - b * 33280;
        unsigned int* xtu = (unsigned int*)xT;
        size_t base = (size_t)b * 66 * 66 * 128;
        size_t idx;
        if (r < 8448) {
            idx = base + r;                                        // row y=0
        } else if (r < 16896) {
            idx = base + (size_t)65 * 66 * 128 + (r - 8448);       // row y=65
        } else {
            int rc = r - 16896;                                    // cols, rows 1..64
            int side = rc >> 13;
            int row = 1 + ((rc & 8191) >> 7);
            int cu = rc & 127;
            idx = base + ((size_t)row * 66 + (side ? 65 : 0)) * 128 + cu;
        }
        xtu[idx] = 0;
    }
}

// ---- fused: offset GEMM prologue + deformable sampling + MFMA GEMM + BN + ReLU ----
__global__ __launch_bounds__(512) void dcn_fused(
        const unsigned short* __restrict__ xT,
        const unsigned short* __restrict__ wOB,
        const unsigned short* __restrict__ wB,
        const float* __restrict__ b_off,
        const float* __restrict__ bias, const float* __restrict__ gamma,
        const float* __restrict__ beta, const float* __restrict__ rmean,
        const float* __restrict__ rvar, float* __restrict__ out) {
    // union'd LDS: {s_po, s_cw} fixed; sA region aliases sOff (prologue) and sOut (epilogue)
    __shared__ __align__(16) unsigned char smem[33280];
    int4*   s_po = (int4*)smem;                                 // [288] corner offsets
    float4* s_cw = (float4*)(smem + 4608);                      // [288] bilinear weights
    unsigned short* sA = (unsigned short*)(smem + 9216);        // [8][32*40] slice bufs
    float* sOff = (float*)(smem + 9216);                        // [2][32][33] offset partials
    float (*sOut)[260] = (float(*)[260])smem;                   // epilogue kh-combine

    int id = blockIdx.x;                        // 512 blocks
    int xcd = id & 7, sl = id >> 3;
    int b = xcd >> 1;
    int h = (xcd & 1) * 32 + (sl & 31);
    int pxbase = (sl >> 5) * 32;

    int tid = threadIdx.x;
    int lane = tid & 63, q = tid >> 6;
    int ln = lane & 15, lk = lane >> 4;
    int nb = q & 3, kh = q >> 2;                // main-loop consumer role

    const unsigned short* xTfull = xT + (size_t)b * XT_B;
    const bf16x8* wOBv = (const bf16x8*)wOB;
    const bf16x8* wBv  = (const bf16x8*)wB;

    // ---- offset-conv prologue: om = xT . wOB  (M=32 px, N=32 oc, K=2304) ----
    {
        int omt = q & 1, ont = (q >> 1) & 1, okq = q >> 2;   // wave -> (m-tile, n-tile, K-half)
        int opx = pxbase + omt * 16 + ln;
        int oposbase = (h + 1) * 66 + opx + 1;
        f32x4 oacc = {0.f, 0.f, 0.f, 0.f};
        for (int s = okq * 36; s < okq * 36 + 36; ++s) {
            int cc = s / 9, kt = s - cc * 9;
            int pos = oposbase + (kt / 3 - 1) * 66 + (kt % 3 - 1);
            bf16x8 af  = *(const bf16x8*)&xTfull[(size_t)pos * 256 + cc * 32 + lk * 8];
            bf16x8 bfo = wOBv[((size_t)s * 32 + ont * 16 + ln) * 4 + lk];
            oacc = __builtin_amdgcn_mfma_f32_16x16x32_bf16(af, bfo, oacc, 0, 0, 0);
        }
#pragma unroll
        for (int r = 0; r < 4; ++r)
            sOff[(okq * 32 + omt * 16 + lk * 4 + r) * 33 + ont * 16 + ln] = oacc[r];
    }
    __syncthreads();

    // ---- bilinear metadata from in-LDS offsets; sigmoid here ----
    for (int p = tid; p < 288; p += 512) {
        int k = p >> 5, pwl = p & 31, pw = pxbase + pwl;
        float dy = sOff[pwl * 33 + k]        + sOff[(32 + pwl) * 33 + k]        + b_off[k];
        float dx = sOff[pwl * 33 + k + 9]    + sOff[(32 + pwl) * 33 + k + 9]    + b_off[k + 9];
        float mp = sOff[pwl * 33 + k + 18]   + sOff[(32 + pwl) * 33 + k + 18]   + b_off[k + 18];
        float mv = 1.f / (1.f + __expf(-mp));
        float py  = (float)h  + (float)(k / 3 - 1) + dy;
        float pxf = (float)pw + (float)(k % 3 - 1) + dx;
        float y0f = floorf(py), x0f = floorf(pxf);
        int y0 = (int)y0f, x0 = (int)x0f;
        float ly = py - y0f, lx = pxf - x0f;
        int y0c = min(max(y0, -1), 64), y1c = min(max(y0 + 1, -1), 64);
        int x0c = min(max(x0, -1), 64), x1c = min(max(x0 + 1, -1), 64);
        int ry0 = (y0c + 1) * 66, ry1 = (y1c + 1) * 66;
        s_po[p] = make_int4(ry0 + x0c + 1, ry0 + x1c + 1, ry1 + x0c + 1, ry1 + x1c + 1);
        s_cw[p] = make_float4((1.f - ly) * (1.f - lx) * mv, (1.f - ly) * lx * mv,
                              ly * (1.f - lx) * mv,         ly * lx * mv);
    }

    // producer role: thread covers slice-slot sl4, 8 channels cg8*8.., pixel pxl
    int pxl = tid & 31, cg8 = (tid >> 5) & 3, sl4 = tid >> 7;
    int khp = sl4 >> 1, ip = sl4 & 1;           // producer slice = khp*36 + 2*phase + ip
    const unsigned short* xTb = xTfull + cg8 * 8;

    f32x4 zf = {0.f, 0.f, 0.f, 0.f};
    f32x4 acc[2][4] = {{zf, zf, zf, zf}, {zf, zf, zf, zf}};

    uint4 C00, C01, C10, C11;

#define LOADS(s) do { int s_ = (s); int cc_ = s_ / 9; int kt_ = s_ - cc_ * 9;  \
        int4 o4_ = s_po[kt_ * 32 + pxl];                                       \
        const unsigned short* cb_ = xTb + cc_ * 32;                            \
        C00 = *(const uint4*)(cb_ + (size_t)o4_.x * 256);                      \
        C01 = *(const uint4*)(cb_ + (size_t)o4_.y * 256);                      \
        C10 = *(const uint4*)(cb_ + (size_t)o4_.z * 256);                      \
        C11 = *(const uint4*)(cb_ + (size_t)o4_.w * 256);                      \
    } while (0)

#define WRITEA(s, buf) do { int s_ = (s); int kt_ = s_ - (s_ / 9) * 9;         \
        float4 w_ = s_cw[kt_ * 32 + pxl];                                      \
        uint4 pk_;                                                             \
        pk_.x = pkbf(w_.x*bflo(C00.x)+w_.y*bflo(C01.x)+w_.z*bflo(C10.x)+w_.w*bflo(C11.x), \
                     w_.x*bfhi(C00.x)+w_.y*bfhi(C01.x)+w_.z*bfhi(C10.x)+w_.w*bfhi(C11.x)); \
        pk_.y = pkbf(w_.x*bflo(C00.y)+w_.y*bflo(C01.y)+w_.z*bflo(C10.y)+w_.w*bflo(C11.y), \
                     w_.x*bfhi(C00.y)+w_.y*bfhi(C01.y)+w_.z*bfhi(C10.y)+w_.w*bfhi(C11.y)); \
        pk_.z = pkbf(w_.x*bflo(C00.z)+w_.y*bflo(C01.z)+w_.z*bflo(C10.z)+w_.w*bflo(C11.z), \
                     w_.x*bfhi(C00.z)+w_.y*bfhi(C01.z)+w_.z*bfhi(C10.z)+w_.w*bfhi(C11.z)); \
        pk_.w = pkbf(w_.x*bflo(C00.w)+w_.y*bflo(C01.w)+w_.z*bflo(C10.w)+w_.w*bflo(C11.w), \
                     w_.x*bfhi(C00.w)+w_.y*bfhi(C01.w)+w_.z*bfhi(C10.w)+w_.w*bfhi(C11.w)); \
        *(uint4*)&sA[(buf) * 1280 + pxl * 40 + cg8 * 8] = pk_;                 \
    } while (0)

    __syncthreads();   // metadata ready; sOff no longer needed (sA may overwrite)

    // software pipeline prologue
    LOADS(khp * 36 + ip);
    WRITEA(khp * 36 + ip, sl4);
    LOADS(khp * 36 + 2 + ip);
    bf16x8 bf[4], nbf[4];
#pragma unroll
    for (int j = 0; j < 4; ++j)
        bf[j] = wBv[((size_t)(kh * 36) * 256 + nb * 64 + j * 16 + ln) * 4 + lk];
    __syncthreads();

    for (int g = 0; g < 18; ++g) {
        if (g + 1 < 18) WRITEA(khp * 36 + 2 * (g + 1) + ip, ((g + 1) & 1) * 4 + sl4);
        if (g + 2 < 18) LOADS(khp * 36 + 2 * (g + 2) + ip);
#pragma unroll
        for (int i = 0; i < 2; ++i) {           // consume this wave's 2 slices
            int off = 2 * g + i;                // 0..35 within K-half
            int buf = (g & 1) * 4 + kh * 2 + i;
            bf16x8 af0 = *(const bf16x8*)&sA[buf * 1280 + ln * 40 + lk * 8];
            bf16x8 af1 = *(const bf16x8*)&sA[buf * 1280 + (16 + ln) * 40 + lk * 8];
            bool more = (off + 1 < 36);
            if (more) {
                int sn = kh * 36 + off + 1;
#pragma unroll
                for (int j = 0; j < 4; ++j)
                    nbf[j] = wBv[((size_t)sn * 256 + nb * 64 + j * 16 + ln) * 4 + lk];
            }
#pragma unroll
            for (int j = 0; j < 4; ++j) {
                acc[0][j] = __builtin_amdgcn_mfma_f32_16x16x32_bf16(af0, bf[j], acc[0][j], 0, 0, 0);
                acc[1][j] = __builtin_amdgcn_mfma_f32_16x16x32_bf16(af1, bf[j], acc[1][j], 0, 0, 0);
            }
            if (more) {
#pragma unroll
                for (int j = 0; j < 4; ++j) bf[j] = nbf[j];
            }
        }
        __syncthreads();
    }
#undef LOADS
#undef WRITEA

    // kh-combine + BN + ReLU epilogue (sOut aliases the K-phase LDS)
    if (kh == 1) {
#pragma unroll
        for (int m = 0; m < 2; ++m)
#pragma unroll
            for (int j = 0; j < 4; ++j) {
                int oc = nb * 64 + j * 16 + ln;
#pragma unroll
                for (int r = 0; r < 4; ++r)
                    sOut[m * 16 + lk * 4 + r][oc] = acc[m][j][r];
            }
    }
    __syncthreads();
    if (kh == 0) {
#pragma unroll
        for (int m = 0; m < 2; ++m)
#pragma unroll
            for (int j = 0; j < 4; ++j) {
                int oc = nb * 64 + j * 16 + ln;
                float inv = gamma[oc] * rsqrtf(rvar[oc] + 1e-5f);
                float sh  = beta[oc] - rmean[oc] * inv + bias[oc] * inv;
                int row = m * 16 + lk * 4;
                float4 rr;
                rr.x = fmaxf((acc[m][j][0] + sOut[row + 0][oc]) * inv + sh, 0.f);
                rr.y = fmaxf((acc[m][j][1] + sOut[row + 1][oc]) * inv + sh, 0.f);
                rr.z = fmaxf((acc[m][j][2] + sOut[row + 2][oc]) * inv + sh, 0.f);
                rr.w = fmaxf((acc[m][j][3] + sOut[row + 3][oc]) * inv + sh, 0.f);
                size_t oi = (((size_t)b * 256 + oc) * 64 + h) * 64 + pxbase + row;
                *(float4*)(out + oi) = rr;
            }
    }
}

extern "C" void kernel_launch(void* const* d_in, const int* in_sizes, int n_in,
                              void* d_out, int out_size, void* d_ws, size_t ws_size,
                              hipStream_t stream) {
    const float* x      = (const float*)d_in[0];
    const float* w_off  = (const float*)d_in[1];
    const float* b_off  = (const float*)d_in[2];
    const float* weight = (const float*)d_in[3];
    const float* bias   = (const float*)d_in[4];
    const float* gamma  = (const float*)d_in[5];
    const float* beta   = (const float*)d_in[6];
    const float* rmean  = (const float*)d_in[7];
    const float* rvar   = (const float*)d_in[8];
    float* out = (float*)d_out;

    unsigned short* wB  = (unsigned short*)d_ws;             // 589824 bf16
    unsigned short* wOB = wB + 589824;                       // 73728 bf16
    unsigned short* xT  = wOB + 73728;                       // 4 * 66*66*256 bf16

    hipLaunchKernelGGL(prep_all, dim3(3624), dim3(256), 0, stream,
                       weight, w_off, x, wB, wOB, xT);
    hipLaunchKernelGGL(dcn_fused, dim3(512), dim3(512), 0, stream,
                       xT, wOB, wB, b_off, bias, gamma, beta, rmean, rvar, out);
}